// Round 21
// baseline (291.501 us; speedup 1.0000x reference)
//
#include <hip/hip_runtime.h>

// SlotAttention (bf16 hln, single layout, MFMA). Round-18 structure +
// k4 tile stride 34 (LDS 40,064 B -> 4 blocks/CU, no scheduling tail).
//   - 6-layer linear stack folded into 66->128 affine (Wh, bh).
//   - k,v folded out of N.
//   - hln bf16 row-major [NB][128] (64 MB, L3-resident).
//   - k2: single-bf16 MFMA GEMM; E pre-converted bf16 in LDS.
//   - k4 x3: 1024 blocks x 4 waves x 2 pipelined 32-row tiles; transposed
//     per-wave tile stride 34; per-slab partials (no atomics).
//   - k5: 512 threads; GEMVs as 32-iter partials + LDS tree reduce.

#define B_  8
#define N_  32768
#define NB_ (B_ * N_)
#define D_  128
#define S_  8

typedef unsigned int u32;
typedef unsigned short u16;
typedef __attribute__((ext_vector_type(8))) short bf16x8;
typedef __attribute__((ext_vector_type(4))) float f32x4;

__device__ inline u32 bfr1(float x) {  // f32 -> bf16 (RNE)
    u32 u = __float_as_uint(x);
    return (u + 0x7FFFu + ((u >> 16) & 1u)) >> 16;
}
__device__ inline u32 bfpack2(u32 lo, u32 hi) { return lo | (hi << 16); }

// threefry2x32, key = (0, 42)
__device__ inline void threefry42(u32 c0, u32 c1, u32& o0, u32& o1) {
    const u32 k0 = 0u, k1 = 42u, k2 = 0x1BD11BDAu ^ 0u ^ 42u;
    const u32 ks[3] = {k0, k1, k2};
    u32 x0 = c0 + k0, x1 = c1 + k1;
    const int rA[4] = {13, 15, 26, 6}, rB[4] = {17, 29, 16, 24};
#pragma unroll
    for (int i = 0; i < 5; i++) {
#pragma unroll
        for (int k = 0; k < 4; k++) {
            int r = (i & 1) ? rB[k] : rA[k];
            x0 += x1;
            x1 = (x1 << r) | (x1 >> (32 - r));
            x1 ^= x0;
        }
        x0 += ks[(i + 1) % 3];
        x1 += ks[(i + 2) % 3] + (u32)(i + 1);
    }
    o0 = x0; o1 = x1;
}

// jax uniform(-0.99999994, 1) -> sqrt(2)*erfinv
__device__ inline float bits_to_normal(u32 b) {
    float f = __uint_as_float((b >> 9) | 0x3f800000u) - 1.0f;
    const float lo = -0.99999994f;
    float r = fmaxf(lo, f * 1.99999994f + lo);
    float w = -log1pf(-r * r);
    float p;
    if (w < 5.0f) {
        w -= 2.5f;
        p = 2.81022636e-08f;
        p = fmaf(p, w, 3.43273939e-07f);
        p = fmaf(p, w, -3.5233877e-06f);
        p = fmaf(p, w, -4.39150654e-06f);
        p = fmaf(p, w, 0.00021858087f);
        p = fmaf(p, w, -0.00125372503f);
        p = fmaf(p, w, -0.00417768164f);
        p = fmaf(p, w, 0.246640727f);
        p = fmaf(p, w, 1.50140941f);
    } else {
        w = sqrtf(w) - 3.0f;
        p = -0.000200214257f;
        p = fmaf(p, w, 0.000100950558f);
        p = fmaf(p, w, 0.00134934322f);
        p = fmaf(p, w, -0.00367342844f);
        p = fmaf(p, w, 0.00573950773f);
        p = fmaf(p, w, -0.0076224613f);
        p = fmaf(p, w, 0.00943887047f);
        p = fmaf(p, w, 1.00167406f);
        p = fmaf(p, w, 2.83297682f);
    }
    return 1.41421356f * (p * r);
}

// 128-thread block sum (k3 only)
__device__ inline float block128_sum(float v, float* red) {
#pragma unroll
    for (int o = 32; o; o >>= 1) v += __shfl_down(v, o);
    __syncthreads();
    if ((threadIdx.x & 63) == 0) red[threadIdx.x >> 6] = v;
    __syncthreads();
    return red[0] + red[1];
}

// emit_q for 128-thread k3
__device__ void emit_q(float x, int bs,
                       const float* lnsg, const float* lnsb,
                       const float* wq, const float* bq,
                       const float* wkT, const float* bk,
                       float* qt, float* qc,
                       float* shA, float* red) {
    int t = threadIdx.x;
    float m = block128_sum(x, red) * (1.0f / 128.0f);
    float e = x - m;
    float var = block128_sum(e * e, red) * (1.0f / 128.0f);
    float inv = rsqrtf(var + 1e-5f);
    __syncthreads();
    shA[t] = fmaf(e * inv, lnsg[t], lnsb[t]);
    __syncthreads();
    float q = bq[t];
#pragma unroll 4
    for (int i = 0; i < 128; i++) q = fmaf(shA[i], wq[i * 128 + t], q);
    __syncthreads();
    shA[t] = q;
    __syncthreads();
    float a2 = 0.f;
#pragma unroll 4
    for (int j = 0; j < 128; j++) a2 = fmaf(wkT[j * 128 + t], shA[j], a2);
    const float scale = 0.08838834764831845f;  // 128^-0.5
    qt[bs * 128 + t] = a2 * scale;
    float pr = block128_sum(shA[t] * bk[t], red);
    if (t == 0) qc[bs] = pr * scale;
}

// ---------- K0: transpose gru weights + wk ----------

__global__ __launch_bounds__(256) void k0_transpose(
    const float* __restrict__ wih, const float* __restrict__ whh,
    const float* __restrict__ wk,
    float* __restrict__ wihT, float* __restrict__ whhT, float* __restrict__ wkT) {
    int idx = blockIdx.x * 256 + threadIdx.x;
    if (idx < 49152) {
        int d = idx / 384, g = idx % 384;
        wihT[idx] = wih[g * 128 + d];
    } else if (idx < 98304) {
        int o = idx - 49152;
        int d = o / 384, g = o % 384;
        whhT[o] = whh[g * 128 + d];
    } else if (idx < 114688) {
        int o = idx - 98304;
        int j = o >> 7, tcol = o & 127;
        wkT[o] = wk[tcol * 128 + j];
    }
}

// ---------- K1: fold weights, init slots, bf16 W ----------

__global__ __launch_bounds__(256) void k1_setup(
    const float* __restrict__ w0, const float* __restrict__ b0,
    const float* __restrict__ w1, const float* __restrict__ b1,
    const float* __restrict__ w2, const float* __restrict__ b2,
    const float* __restrict__ w3, const float* __restrict__ b3,
    const float* __restrict__ w4, const float* __restrict__ b4,
    const float* __restrict__ w5, const float* __restrict__ b5,
    const float* __restrict__ w7, const float* __restrict__ b7,
    const float* __restrict__ mu, const float* __restrict__ sg,
    float* __restrict__ Wh, float* __restrict__ bh, float* __restrict__ slots,
    u16* __restrict__ whiT) {
    __shared__ float A[192], Bt[96], bb[64], bb2[32];
    __shared__ float stats[2];
    int t = threadIdx.x;
    for (int i = t; i < 192; i += 256) A[i] = w0[i];
    for (int i = t; i < 64; i += 256) bb[i] = b0[i];
    __syncthreads();
    const float* wl[5] = {w1, w2, w3, w4, w5};
    const float* bl[5] = {b1, b2, b3, b4, b5};
    int kin = 64;
    for (int l = 0; l < 5; l++) {
        const float* w = wl[l];
        const float* bias = bl[l];
        if (t < 96) {
            int i = t / 32, j = t % 32;
            float acc = 0.f;
            for (int k = 0; k < kin; k++) acc += A[i * kin + k] * w[k * 32 + j];
            Bt[i * 32 + j] = acc;
        } else if (t < 128) {
            int j = t - 96;
            float acc = bias[j];
            for (int k = 0; k < kin; k++) acc += bb[k] * w[k * 32 + j];
            bb2[j] = acc;
        }
        __syncthreads();
        if (t < 96) A[t] = Bt[t];
        if (t < 32) bb[t] = bb2[t];
        __syncthreads();
        kin = 32;
    }
    for (int idx = t; idx < 66 * 128; idx += 256) {
        int i = idx >> 7, j = idx & 127;
        float acc = w7[idx];
        if (i < 3) {
            for (int k = 0; k < 32; k++) acc += A[i * 32 + k] * w7[(66 + k) * 128 + j];
        }
        Wh[idx] = acc;
    }
    for (int j = t; j < 128; j += 256) {
        float acc = b7[j];
        for (int k = 0; k < 32; k++) acc += bb[k] * w7[(66 + k) * 128 + j];
        bh[j] = acc;
    }
    if (t == 0) {
        float s1 = 0.f, s2 = 0.f;
        for (int d = 0; d < 128; d++) { s1 += mu[d]; s2 += sg[d]; }
        float mmu = s1 / 128.f, msg = s2 / 128.f;
        float ss = 0.f;
        for (int d = 0; d < 128; d++) { float e = sg[d] - msg; ss += e * e; }
        stats[0] = mmu;
        stats[1] = sqrtf(64.f * ss / 8191.f);
    }
    __syncthreads();
    for (int idx = t; idx < 128 * 96; idx += 256) {
        int col = idx / 96, k = idx - col * 96;
        float v = (k < 66) ? Wh[k * 128 + col] : 0.f;
        whiT[idx] = (u16)bfr1(v);
    }
    float mean = stats[0], sd = stats[1];
    for (int p = t; p < 8192; p += 256) {
        u32 o0, o1;
        threefry42(0u, (u32)p, o0, o1);
        slots[p] = fmaf(sd, bits_to_normal(o0 ^ o1), mean);
    }
}

// ---------- K2: single-bf16 MFMA build of hln ----------

__global__ __launch_bounds__(256) void k2_hln(
    const float* __restrict__ inputs, const float* __restrict__ embed,
    const u16* __restrict__ whiT, const float* __restrict__ bh,
    const float* __restrict__ g, const float* __restrict__ bbias,
    u16* __restrict__ hlnb) {
    __shared__ __align__(16) char smem[34816];  // ebuf u16[128][104] / T u16[128][136]
    __shared__ float bhl[128], gl[128], bl[128];
    int t = threadIdx.x;
    u16* ebuf = (u16*)smem;
    size_t rbase = (size_t)blockIdx.x * 128;
    for (int idx = t; idx < 384; idx += 256)
        ebuf[(idx / 3) * 104 + (idx % 3)] = (u16)bfr1(inputs[rbase * 3 + idx]);
    for (int idx = t; idx < 128 * 63; idx += 256) {
        int r = idx / 63, i = idx - r * 63;
        ebuf[r * 104 + 3 + i] = (u16)bfr1(embed[rbase * 63 + idx]);
    }
    for (int idx = t; idx < 128 * 30; idx += 256) {
        int r = idx / 30, i = idx - r * 30;
        ebuf[r * 104 + 66 + i] = 0;
    }
    if (t < 128) { bhl[t] = bh[t]; gl[t] = g[t]; bl[t] = bbias[t]; }
    __syncthreads();

    int w = t >> 6, l = t & 63;
    int c16 = l & 15, g4 = l >> 4;
    int wr0 = w * 32;
    float bhc[8], gc[8], bc[8];
#pragma unroll
    for (int nt = 0; nt < 8; nt++) {
        bhc[nt] = bhl[nt * 16 + c16];
        gc[nt] = gl[nt * 16 + c16];
        bc[nt] = bl[nt * 16 + c16];
    }
    f32x4 acc[2][8];
#pragma unroll
    for (int mi = 0; mi < 2; mi++)
#pragma unroll
        for (int nt = 0; nt < 8; nt++)
            acc[mi][nt] = (f32x4){bhc[nt], bhc[nt], bhc[nt], bhc[nt]};

#pragma unroll
    for (int kc = 0; kc < 3; kc++) {
        bf16x8 a0 = *(const bf16x8*)&ebuf[(wr0 + c16) * 104 + kc * 32 + g4 * 8];
        bf16x8 a1 = *(const bf16x8*)&ebuf[(wr0 + 16 + c16) * 104 + kc * 32 + g4 * 8];
#pragma unroll
        for (int nt = 0; nt < 8; nt++) {
            uint4 bw = *(const uint4*)(whiT + (size_t)(nt * 16 + c16) * 96 + kc * 32 + g4 * 8);
            bf16x8 bf = *(bf16x8*)&bw;
            acc[0][nt] = __builtin_amdgcn_mfma_f32_16x16x32_bf16(a0, bf, acc[0][nt], 0, 0, 0);
            acc[1][nt] = __builtin_amdgcn_mfma_f32_16x16x32_bf16(a1, bf, acc[1][nt], 0, 0, 0);
        }
    }

    __syncthreads();
    u16* T = (u16*)smem;           // [128][136]
#pragma unroll
    for (int mi = 0; mi < 2; mi++) {
#pragma unroll
        for (int i = 0; i < 4; i++) {
            float s = 0.f;
#pragma unroll
            for (int nt = 0; nt < 8; nt++) s += acc[mi][nt][i];
            s += __shfl_xor(s, 1); s += __shfl_xor(s, 2);
            s += __shfl_xor(s, 4); s += __shfl_xor(s, 8);
            float m = s * (1.0f / 128.0f);
            float v = 0.f;
#pragma unroll
            for (int nt = 0; nt < 8; nt++) { float d = acc[mi][nt][i] - m; v = fmaf(d, d, v); }
            v += __shfl_xor(v, 1); v += __shfl_xor(v, 2);
            v += __shfl_xor(v, 4); v += __shfl_xor(v, 8);
            float inv = rsqrtf(v * (1.0f / 128.0f) + 1e-5f);
            int row = wr0 + mi * 16 + g4 * 4 + i;
#pragma unroll
            for (int nt = 0; nt < 8; nt++) {
                float val = fmaf((acc[mi][nt][i] - m) * inv, gc[nt], bc[nt]);
                T[row * 136 + nt * 16 + c16] = (u16)bfr1(val);
            }
        }
    }
    __syncthreads();
    {
        int r = t >> 1, hf = t & 1;
        const u16* Tr = T + r * 136 + hf * 64;
        u16* dst = hlnb + (rbase + r) * 128 + hf * 64;
#pragma unroll
        for (int j = 0; j < 8; j++) {
            uint4 v = *(const uint4*)(Tr + j * 8);
            *(uint4*)(dst + j * 8) = v;
        }
    }
}

// ---------- K3: initial q from slots ----------

__global__ __launch_bounds__(128) void k3_q(
    const float* __restrict__ slots,
    const float* __restrict__ lnsg, const float* __restrict__ lnsb,
    const float* __restrict__ wq, const float* __restrict__ bq,
    const float* __restrict__ wkT, const float* __restrict__ bk,
    float* __restrict__ qt, float* __restrict__ qc) {
    __shared__ float shA[128];
    __shared__ float red[2];
    int bs = blockIdx.x;
    float x = slots[bs * 128 + threadIdx.x];
    emit_q(x, bs, lnsg, lnsb, wq, bq, wkT, bk, qt, qc, shA, red);
}

// ---------- K4: MFMA attention, 2 pipelined tiles/wave, stride-34 tile ----------
// LDS = 34816 + 5120 + 128 = 40064 B -> 4 blocks/CU (all 1024 resident).

__global__ __launch_bounds__(256) void k4_attn(
    const uint4* __restrict__ hlnb4,
    const float* __restrict__ qt, const float* __restrict__ qc,
    float* __restrict__ vecp, float* __restrict__ denp) {
    __shared__ __align__(16) u16 tiles[4][128 * 34];   // 34816 B (vlds aliased)
    __shared__ __align__(16) u16 attnP[4][16 * 40];    // 5120 B
    __shared__ float dlds[4][8];
    int t = threadIdx.x;
    int w = t >> 6, l = t & 63;
    int blk = blockIdx.x;
    int b = blk >> 7, slab = blk & 127;
    size_t row0 = (size_t)b * N_ + (size_t)slab * 256 + (size_t)w * 32;
    int c16 = l & 15, g = l >> 4;
    u16* tw = tiles[w];

    bf16x8 qf[4];
#pragma unroll
    for (int kc = 0; kc < 4; kc++) {
        uint4 qu = {0u, 0u, 0u, 0u};
        if (c16 < 8) {
            const float* qp = qt + b * 1024 + c16 * 128 + kc * 32 + g * 8;
            float4 qa = *(const float4*)qp;
            float4 qb = *(const float4*)(qp + 4);
            qu.x = bfpack2(bfr1(qa.x), bfr1(qa.y));
            qu.y = bfpack2(bfr1(qa.z), bfr1(qa.w));
            qu.z = bfpack2(bfr1(qb.x), bfr1(qb.y));
            qu.w = bfpack2(bfr1(qb.z), bfr1(qb.w));
        }
        qf[kc] = *(bf16x8*)&qu;
    }
    float qcv = (c16 < 8) ? qc[b * 8 + c16] : 0.f;

    f32x4 uacc[8];
#pragma unroll
    for (int nt = 0; nt < 8; nt++) uacc[nt] = (f32x4){0.f, 0.f, 0.f, 0.f};
    float denacc = 0.f;

    uint4 st[8];
#pragma unroll
    for (int mt = 0; mt < 2; mt++)
#pragma unroll
        for (int kc = 0; kc < 4; kc++)
            st[mt * 4 + kc] = hlnb4[(row0 + mt * 16 + c16) * 16 + kc * 4 + g];

    for (int tt = 0; tt < 2; tt++) {
        f32x4 dacc[2];
        dacc[0] = (f32x4){0.f, 0.f, 0.f, 0.f};
        dacc[1] = (f32x4){0.f, 0.f, 0.f, 0.f};
#pragma unroll
        for (int mt = 0; mt < 2; mt++) {
#pragma unroll
            for (int kc = 0; kc < 4; kc++) {
                uint4 au = st[mt * 4 + kc];
                dacc[mt] = __builtin_amdgcn_mfma_f32_16x16x32_bf16(*(bf16x8*)&au, qf[kc], dacc[mt], 0, 0, 0);
                int r = mt * 16 + c16;
                int d0 = kc * 32 + g * 8;
                tw[(d0 + 0) * 34 + r] = (u16)(au.x & 0xFFFF);
                tw[(d0 + 1) * 34 + r] = (u16)(au.x >> 16);
                tw[(d0 + 2) * 34 + r] = (u16)(au.y & 0xFFFF);
                tw[(d0 + 3) * 34 + r] = (u16)(au.y >> 16);
                tw[(d0 + 4) * 34 + r] = (u16)(au.z & 0xFFFF);
                tw[(d0 + 5) * 34 + r] = (u16)(au.z >> 16);
                tw[(d0 + 6) * 34 + r] = (u16)(au.w & 0xFFFF);
                tw[(d0 + 7) * 34 + r] = (u16)(au.w >> 16);
            }
        }
        if (tt == 0) {
            size_t rowB = row0 + 128;
#pragma unroll
            for (int mt = 0; mt < 2; mt++)
#pragma unroll
                for (int kc = 0; kc < 4; kc++)
                    st[mt * 4 + kc] = hlnb4[(rowB + mt * 16 + c16) * 16 + kc * 4 + g];
        }
#pragma unroll
        for (int mt = 0; mt < 2; mt++) {
            float pv[4];
#pragma unroll
            for (int r = 0; r < 4; r++) {
                float v = dacc[mt][r] + qcv;
                float mx = v;
                mx = fmaxf(mx, __shfl_xor(mx, 1));
                mx = fmaxf(mx, __shfl_xor(mx, 2));
                mx = fmaxf(mx, __shfl_xor(mx, 4));
                float e = __expf(v - mx);
                float ssum = e;
                ssum += __shfl_xor(ssum, 1);
                ssum += __shfl_xor(ssum, 2);
                ssum += __shfl_xor(ssum, 4);
                float a = (c16 < 8) ? fmaf(e, 1.0f / ssum, 1e-8f) : 0.f;
                pv[r] = a;
                denacc += a;
            }
            uint2 pw;
            pw.x = bfpack2(bfr1(pv[0]), bfr1(pv[1]));
            pw.y = bfpack2(bfr1(pv[2]), bfr1(pv[3]));
            *(uint2*)&attnP[w][c16 * 40 + mt * 16 + g * 4] = pw;
        }
        uint4 afu = *(const uint4*)&attnP[w][c16 * 40 + g * 8];
        bf16x8 af = *(bf16x8*)&afu;
#pragma unroll
        for (int nt = 0; nt < 8; nt++) {
            const u16* tp = tw + (nt * 16 + c16) * 34 + g * 8;
            uint2 blo = *(const uint2*)tp;
            uint2 bhi = *(const uint2*)(tp + 4);
            uint4 bu; bu.x = blo.x; bu.y = blo.y; bu.z = bhi.x; bu.w = bhi.y;
            uacc[nt] = __builtin_amdgcn_mfma_f32_16x16x32_bf16(af, *(bf16x8*)&bu, uacc[nt], 0, 0, 0);
        }
    }
    denacc += __shfl_xor(denacc, 16);
    denacc += __shfl_xor(denacc, 32);
    if (l < 8) dlds[w][l] = denacc;

    __syncthreads();
    float* vlds0 = (float*)&tiles[0][0];
    float* vlds1 = vlds0 + 1024;
    if (w < 2 && g < 2) {
        float* vb = (w == 0) ? vlds0 : vlds1;
#pragma unroll
        for (int nt = 0; nt < 8; nt++)
#pragma unroll
            for (int r = 0; r < 4; r++)
                vb[(g * 4 + r) * 128 + nt * 16 + c16] = uacc[nt][r];
    }
    __syncthreads();
    if (w >= 2 && g < 2) {
        float* vb = (w == 2) ? vlds0 : vlds1;
#pragma unroll
        for (int nt = 0; nt < 8; nt++)
#pragma unroll
            for (int r = 0; r < 4; r++)
                vb[(g * 4 + r) * 128 + nt * 16 + c16] += uacc[nt][r];
    }
    __syncthreads();
    float* vout = vecp + ((size_t)blk << 10);
#pragma unroll
    for (int rep = 0; rep < 4; rep++) {
        int o = rep * 256 + t;
        vout[o] = vlds0[o] + vlds1[o];
    }
    if (t < 8) denp[blk * 8 + t] = dlds[0][t] + dlds[1][t] + dlds[2][t] + dlds[3][t];
}

// ---------- K5: 512-thread parallel update ----------

__device__ inline float sum512(float v, float* red8) {
#pragma unroll
    for (int o = 32; o; o >>= 1) v += __shfl_down(v, o);
    __syncthreads();
    if ((threadIdx.x & 63) == 0) red8[threadIdx.x >> 6] = v;
    __syncthreads();
    float s = 0.f;
#pragma unroll
    for (int i = 0; i < 8; i++) s += red8[i];
    return s;
}

__device__ inline float reduce4(float part, float* praw, int qq, int d) {
    __syncthreads();
    praw[qq * 128 + d] = part;
    __syncthreads();
    return praw[d] + praw[128 + d] + praw[256 + d] + praw[384 + d];
}

__global__ __launch_bounds__(512) void k5_update(
    const float* __restrict__ vecp, const float* __restrict__ denp,
    const float* __restrict__ wv, const float* __restrict__ bv,
    const float* __restrict__ wihT, const float* __restrict__ whhT,
    const float* __restrict__ bih, const float* __restrict__ bhh,
    const float* __restrict__ lnfg, const float* __restrict__ lnfb,
    const float* __restrict__ m1w, const float* __restrict__ m1b,
    const float* __restrict__ m2w, const float* __restrict__ m2b,
    float* __restrict__ slots,
    const float* __restrict__ lnsg, const float* __restrict__ lnsb,
    const float* __restrict__ wq, const float* __restrict__ bq,
    const float* __restrict__ wkT, const float* __restrict__ bk,
    float* __restrict__ qt, float* __restrict__ qc,
    float* __restrict__ out, int compute_q, int write_out) {
    __shared__ float sA[128], sB[128], sC[128], sH[128], sQ[128];
    __shared__ float praw[512];
    __shared__ float red8[8];
    __shared__ float gsc[6][512];
    int t = threadIdx.x;
    int bs = blockIdx.x;
    int b = bs >> 3, slot = bs & 7;
    int d = t & 127, qq = t >> 7;

    float dvp = (t < 128) ? denp[((size_t)(b * 128) + t) * 8 + slot] : 0.f;
    float dv = sum512(dvp, red8);

    float vs = 0.f;
    const float* vp0 = vecp + (((size_t)(b * 128 + qq * 32)) << 10) + slot * 128 + d;
#pragma unroll 8
    for (int s = 0; s < 32; s++) vs += vp0[(size_t)s << 10];
    float vtot = reduce4(vs, praw, qq, d);
    if (qq == 0) { sA[d] = vtot / dv; sC[d] = slots[bs * 128 + d]; }
    __syncthreads();

    float up = 0.f;
    {
        const float* wvp = wv + (size_t)(qq * 32) * 128 + d;
#pragma unroll 8
        for (int i = 0; i < 32; i++) up = fmaf(sA[qq * 32 + i], wvp[i * 128], up);
    }
    float updt = reduce4(up, praw, qq, d) + bv[d];
    if (qq == 0) sB[d] = updt;
    __syncthreads();

#pragma unroll 1
    for (int gx = 0; gx < 3; gx++) {
        int g = gx * 128 + d;
        float ap = 0.f, hp = 0.f;
        const float* wi = wihT + (size_t)(qq * 32) * 384 + g;
        const float* wh = whhT + (size_t)(qq * 32) * 384 + g;
#pragma unroll 8
        for (int i = 0; i < 32; i++) {
            ap = fmaf(sB[qq * 32 + i], wi[i * 384], ap);
            hp = fmaf(sC[qq * 32 + i], wh[i * 384], hp);
        }
        gsc[gx * 2][t] = ap;
        gsc[gx * 2 + 1][t] = hp;
    }
    __syncthreads();
    float gi0 = gsc[0][d] + gsc[0][128 + d] + gsc[0][256 + d] + gsc[0][384 + d] + bih[d];
    float gh0 = gsc[1][d] + gsc[1][128 + d] + gsc[1][256 + d] + gsc[1][384 + d] + bhh[d];
    float gi1 = gsc[2][d] + gsc[2][128 + d] + gsc[2][256 + d] + gsc[2][384 + d] + bih[128 + d];
    float gh1 = gsc[3][d] + gsc[3][128 + d] + gsc[3][256 + d] + gsc[3][384 + d] + bhh[128 + d];
    float gi2 = gsc[4][d] + gsc[4][128 + d] + gsc[4][256 + d] + gsc[4][384 + d] + bih[256 + d];
    float gh2 = gsc[5][d] + gsc[5][128 + d] + gsc[5][256 + d] + gsc[5][384 + d] + bhh[256 + d];
    float rg = 1.f / (1.f + expf(-(gi0 + gh0)));
    float zg = 1.f / (1.f + expf(-(gi1 + gh1)));
    float ng = tanhf(fmaf(rg, gh2, gi2));
    float hnew = (1.f - zg) * ng + zg * sC[d];
    __syncthreads();
    if (qq == 0) sH[d] = hnew;
    __syncthreads();

    float xh = (t < 128) ? sH[t] : 0.f;
    float mh = sum512(xh, red8) * (1.0f / 128.0f);
    float eh = xh - mh;
    float vh = sum512((t < 128) ? eh * eh : 0.f, red8) * (1.0f / 128.0f);
    float invh = rsqrtf(vh + 1e-5f);
    __syncthreads();
    if (t < 128) sA[t] = fmaf(eh * invh, lnfg[t], lnfb[t]);
    __syncthreads();

    float p1 = 0.f;
    {
        const float* m1p = m1w + (size_t)(qq * 32) * 128 + d;
#pragma unroll 8
        for (int i = 0; i < 32; i++) p1 = fmaf(sA[qq * 32 + i], m1p[i * 128], p1);
    }
    float m1v = reduce4(p1, praw, qq, d) + m1b[d];
    if (qq == 0) sB[d] = m1v;
    __syncthreads();

    float p2 = 0.f;
    {
        const float* m2p = m2w + (size_t)(qq * 32) * 128 + d;
#pragma unroll 8
        for (int i = 0; i < 32; i++) p2 = fmaf(sB[qq * 32 + i], m2p[i * 128], p2);
    }
    float m2v = reduce4(p2, praw, qq, d) + m2b[d];
    float snew = sH[d] + m2v;
    __syncthreads();
    if (qq == 0) {
        slots[bs * 128 + d] = snew;
        if (write_out) out[bs * 128 + d] = snew;
        sH[d] = snew;
    }
    __syncthreads();

    if (compute_q) {
        float xs = (t < 128) ? sH[t] : 0.f;
        float ms = sum512(xs, red8) * (1.0f / 128.0f);
        float es = xs - ms;
        float vs2 = sum512((t < 128) ? es * es : 0.f, red8) * (1.0f / 128.0f);
        float invs = rsqrtf(vs2 + 1e-5f);
        __syncthreads();
        if (t < 128) sA[t] = fmaf(es * invs, lnsg[t], lnsb[t]);
        __syncthreads();
        float pq = 0.f;
        {
            const float* wqp = wq + (size_t)(qq * 32) * 128 + d;
#pragma unroll 8
            for (int i = 0; i < 32; i++) pq = fmaf(sA[qq * 32 + i], wqp[i * 128], pq);
        }
        float qv = reduce4(pq, praw, qq, d) + bq[d];
        if (qq == 0) sQ[d] = qv;
        __syncthreads();
        float pa = 0.f;
        {
            const float* wkp = wkT + (size_t)(qq * 32) * 128 + d;
#pragma unroll 8
            for (int j = 0; j < 32; j++) pa = fmaf(wkp[j * 128], sQ[qq * 32 + j], pa);
        }
        const float scale = 0.08838834764831845f;
        float a2 = reduce4(pa, praw, qq, d) * scale;
        if (qq == 0) qt[bs * 128 + d] = a2;
        float xpr = (t < 128) ? sQ[t] * bk[t] : 0.f;
        float pr = sum512(xpr, red8);
        if (t == 0) qc[bs] = pr * scale;
    }
}

// ---------- launch ----------

extern "C" void kernel_launch(void* const* d_in, const int* in_sizes, int n_in,
                              void* d_out, int out_size, void* d_ws, size_t ws_size,
                              hipStream_t stream) {
    const float* inputs = (const float*)d_in[0];
    const float* embed  = (const float*)d_in[1];
    const float* mu     = (const float*)d_in[2];
    const float* sg     = (const float*)d_in[3];
    const float* w0 = (const float*)d_in[4];  const float* b0 = (const float*)d_in[5];
    const float* w1 = (const float*)d_in[6];  const float* b1 = (const float*)d_in[7];
    const float* w2 = (const float*)d_in[8];  const float* b2 = (const float*)d_in[9];
    const float* w3 = (const float*)d_in[10]; const float* b3 = (const float*)d_in[11];
    const float* w4 = (const float*)d_in[12]; const float* b4 = (const float*)d_in[13];
    const float* w5 = (const float*)d_in[14]; const float* b5 = (const float*)d_in[15];
    const float* w7 = (const float*)d_in[16]; const float* b7 = (const float*)d_in[17];
    const float* wq = (const float*)d_in[18]; const float* bq = (const float*)d_in[19];
    const float* wk = (const float*)d_in[20]; const float* bk = (const float*)d_in[21];
    const float* wv = (const float*)d_in[22]; const float* bv = (const float*)d_in[23];
    const float* ln_in_g = (const float*)d_in[24]; const float* ln_in_b = (const float*)d_in[25];
    const float* ln_sl_g = (const float*)d_in[26]; const float* ln_sl_b = (const float*)d_in[27];
    const float* ln_ff_g = (const float*)d_in[28]; const float* ln_ff_b = (const float*)d_in[29];
    const float* gwih = (const float*)d_in[30]; const float* gwhh = (const float*)d_in[31];
    const float* gbih = (const float*)d_in[32]; const float* gbhh = (const float*)d_in[33];
    const float* m1w = (const float*)d_in[34]; const float* m1b = (const float*)d_in[35];
    const float* m2w = (const float*)d_in[36]; const float* m2b = (const float*)d_in[37];

    char* ws = (char*)d_ws;
    u16* hlnb = (u16*)ws;
    size_t off = (size_t)NB_ * 128 * 2;  // 64 MB bf16 hln row-major
    float* Wh    = (float*)(ws + off); off += 66 * 128 * 4;
    float* bh    = (float*)(ws + off); off += 128 * 4;
    float* slots = (float*)(ws + off); off += 64 * 128 * 4;
    float* qt    = (float*)(ws + off); off += 64 * 128 * 4;
    float* qc    = (float*)(ws + off); off += 64 * 4;
    float* vecp  = (float*)(ws + off); off += (size_t)1024 * 1024 * 4;  // 4 MB
    float* denp  = (float*)(ws + off); off += 1024 * 8 * 4;
    float* wihT  = (float*)(ws + off); off += 384 * 128 * 4;
    float* whhT  = (float*)(ws + off); off += 384 * 128 * 4;
    float* wkT   = (float*)(ws + off); off += 128 * 128 * 4;
    u16* whiT    = (u16*)(ws + off); off += 128 * 96 * 2;

    k0_transpose<<<448, 256, 0, stream>>>(gwih, gwhh, wk, wihT, whhT, wkT);
    k1_setup<<<1, 256, 0, stream>>>(w0, b0, w1, b1, w2, b2, w3, b3, w4, b4, w5, b5,
                                    w7, b7, mu, sg, Wh, bh, slots, whiT);
    k2_hln<<<NB_ / 128, 256, 0, stream>>>(inputs, embed, whiT, bh,
                                          ln_in_g, ln_in_b, hlnb);
    k3_q<<<64, 128, 0, stream>>>(slots, ln_sl_g, ln_sl_b, wq, bq, wkT, bk, qt, qc);
    for (int it = 0; it < 3; it++) {
        k4_attn<<<1024, 256, 0, stream>>>((const uint4*)hlnb, qt, qc, vecp, denp);
        k5_update<<<64, 512, 0, stream>>>(vecp, denp, wv, bv, wihT, whhT, gbih, gbhh,
                                          ln_ff_g, ln_ff_b, m1w, m1b, m2w, m2b, slots,
                                          ln_sl_g, ln_sl_b, wq, bq, wkT, bk, qt, qc,
                                          (float*)d_out, (it < 2) ? 1 : 0, (it == 2) ? 1 : 0);
    }
}

// Round 22
// 257.861 us; speedup vs baseline: 1.1305x; 1.1305x over previous
//
#include <hip/hip_runtime.h>

// SlotAttention (bf16 hln, single layout, MFMA). Round-18 structure with
// k4 tile = stride-32 XOR-swizzled (LDS 38,016 B -> 4 blocks/CU) and
// phase-2 B-frags as single aligned ds_read_b128.
//   - 6-layer linear stack folded into 66->128 affine (Wh, bh).
//   - k,v folded out of N.
//   - hln bf16 row-major [NB][128] (64 MB, L3-resident).
//   - k2: single-bf16 MFMA GEMM; E pre-converted bf16 in LDS.
//   - k4 x3: 1024 blocks x 4 waves x 2 pipelined 32-row tiles.
//   - k5: 512 threads; GEMVs as 32-iter partials + LDS tree reduce.

#define B_  8
#define N_  32768
#define NB_ (B_ * N_)
#define D_  128
#define S_  8

typedef unsigned int u32;
typedef unsigned short u16;
typedef __attribute__((ext_vector_type(8))) short bf16x8;
typedef __attribute__((ext_vector_type(4))) float f32x4;

__device__ inline u32 bfr1(float x) {  // f32 -> bf16 (RNE)
    u32 u = __float_as_uint(x);
    return (u + 0x7FFFu + ((u >> 16) & 1u)) >> 16;
}
__device__ inline u32 bfpack2(u32 lo, u32 hi) { return lo | (hi << 16); }

// threefry2x32, key = (0, 42)
__device__ inline void threefry42(u32 c0, u32 c1, u32& o0, u32& o1) {
    const u32 k0 = 0u, k1 = 42u, k2 = 0x1BD11BDAu ^ 0u ^ 42u;
    const u32 ks[3] = {k0, k1, k2};
    u32 x0 = c0 + k0, x1 = c1 + k1;
    const int rA[4] = {13, 15, 26, 6}, rB[4] = {17, 29, 16, 24};
#pragma unroll
    for (int i = 0; i < 5; i++) {
#pragma unroll
        for (int k = 0; k < 4; k++) {
            int r = (i & 1) ? rB[k] : rA[k];
            x0 += x1;
            x1 = (x1 << r) | (x1 >> (32 - r));
            x1 ^= x0;
        }
        x0 += ks[(i + 1) % 3];
        x1 += ks[(i + 2) % 3] + (u32)(i + 1);
    }
    o0 = x0; o1 = x1;
}

// jax uniform(-0.99999994, 1) -> sqrt(2)*erfinv
__device__ inline float bits_to_normal(u32 b) {
    float f = __uint_as_float((b >> 9) | 0x3f800000u) - 1.0f;
    const float lo = -0.99999994f;
    float r = fmaxf(lo, f * 1.99999994f + lo);
    float w = -log1pf(-r * r);
    float p;
    if (w < 5.0f) {
        w -= 2.5f;
        p = 2.81022636e-08f;
        p = fmaf(p, w, 3.43273939e-07f);
        p = fmaf(p, w, -3.5233877e-06f);
        p = fmaf(p, w, -4.39150654e-06f);
        p = fmaf(p, w, 0.00021858087f);
        p = fmaf(p, w, -0.00125372503f);
        p = fmaf(p, w, -0.00417768164f);
        p = fmaf(p, w, 0.246640727f);
        p = fmaf(p, w, 1.50140941f);
    } else {
        w = sqrtf(w) - 3.0f;
        p = -0.000200214257f;
        p = fmaf(p, w, 0.000100950558f);
        p = fmaf(p, w, 0.00134934322f);
        p = fmaf(p, w, -0.00367342844f);
        p = fmaf(p, w, 0.00573950773f);
        p = fmaf(p, w, -0.0076224613f);
        p = fmaf(p, w, 0.00943887047f);
        p = fmaf(p, w, 1.00167406f);
        p = fmaf(p, w, 2.83297682f);
    }
    return 1.41421356f * (p * r);
}

// 128-thread block sum (k3 only)
__device__ inline float block128_sum(float v, float* red) {
#pragma unroll
    for (int o = 32; o; o >>= 1) v += __shfl_down(v, o);
    __syncthreads();
    if ((threadIdx.x & 63) == 0) red[threadIdx.x >> 6] = v;
    __syncthreads();
    return red[0] + red[1];
}

// emit_q for 128-thread k3
__device__ void emit_q(float x, int bs,
                       const float* lnsg, const float* lnsb,
                       const float* wq, const float* bq,
                       const float* wkT, const float* bk,
                       float* qt, float* qc,
                       float* shA, float* red) {
    int t = threadIdx.x;
    float m = block128_sum(x, red) * (1.0f / 128.0f);
    float e = x - m;
    float var = block128_sum(e * e, red) * (1.0f / 128.0f);
    float inv = rsqrtf(var + 1e-5f);
    __syncthreads();
    shA[t] = fmaf(e * inv, lnsg[t], lnsb[t]);
    __syncthreads();
    float q = bq[t];
#pragma unroll 4
    for (int i = 0; i < 128; i++) q = fmaf(shA[i], wq[i * 128 + t], q);
    __syncthreads();
    shA[t] = q;
    __syncthreads();
    float a2 = 0.f;
#pragma unroll 4
    for (int j = 0; j < 128; j++) a2 = fmaf(wkT[j * 128 + t], shA[j], a2);
    const float scale = 0.08838834764831845f;  // 128^-0.5
    qt[bs * 128 + t] = a2 * scale;
    float pr = block128_sum(shA[t] * bk[t], red);
    if (t == 0) qc[bs] = pr * scale;
}

// ---------- K0: transpose gru weights + wk ----------

__global__ __launch_bounds__(256) void k0_transpose(
    const float* __restrict__ wih, const float* __restrict__ whh,
    const float* __restrict__ wk,
    float* __restrict__ wihT, float* __restrict__ whhT, float* __restrict__ wkT) {
    int idx = blockIdx.x * 256 + threadIdx.x;
    if (idx < 49152) {
        int d = idx / 384, g = idx % 384;
        wihT[idx] = wih[g * 128 + d];
    } else if (idx < 98304) {
        int o = idx - 49152;
        int d = o / 384, g = o % 384;
        whhT[o] = whh[g * 128 + d];
    } else if (idx < 114688) {
        int o = idx - 98304;
        int j = o >> 7, tcol = o & 127;
        wkT[o] = wk[tcol * 128 + j];
    }
}

// ---------- K1: fold weights, init slots, bf16 W ----------

__global__ __launch_bounds__(256) void k1_setup(
    const float* __restrict__ w0, const float* __restrict__ b0,
    const float* __restrict__ w1, const float* __restrict__ b1,
    const float* __restrict__ w2, const float* __restrict__ b2,
    const float* __restrict__ w3, const float* __restrict__ b3,
    const float* __restrict__ w4, const float* __restrict__ b4,
    const float* __restrict__ w5, const float* __restrict__ b5,
    const float* __restrict__ w7, const float* __restrict__ b7,
    const float* __restrict__ mu, const float* __restrict__ sg,
    float* __restrict__ Wh, float* __restrict__ bh, float* __restrict__ slots,
    u16* __restrict__ whiT) {
    __shared__ float A[192], Bt[96], bb[64], bb2[32];
    __shared__ float stats[2];
    int t = threadIdx.x;
    for (int i = t; i < 192; i += 256) A[i] = w0[i];
    for (int i = t; i < 64; i += 256) bb[i] = b0[i];
    __syncthreads();
    const float* wl[5] = {w1, w2, w3, w4, w5};
    const float* bl[5] = {b1, b2, b3, b4, b5};
    int kin = 64;
    for (int l = 0; l < 5; l++) {
        const float* w = wl[l];
        const float* bias = bl[l];
        if (t < 96) {
            int i = t / 32, j = t % 32;
            float acc = 0.f;
            for (int k = 0; k < kin; k++) acc += A[i * kin + k] * w[k * 32 + j];
            Bt[i * 32 + j] = acc;
        } else if (t < 128) {
            int j = t - 96;
            float acc = bias[j];
            for (int k = 0; k < kin; k++) acc += bb[k] * w[k * 32 + j];
            bb2[j] = acc;
        }
        __syncthreads();
        if (t < 96) A[t] = Bt[t];
        if (t < 32) bb[t] = bb2[t];
        __syncthreads();
        kin = 32;
    }
    for (int idx = t; idx < 66 * 128; idx += 256) {
        int i = idx >> 7, j = idx & 127;
        float acc = w7[idx];
        if (i < 3) {
            for (int k = 0; k < 32; k++) acc += A[i * 32 + k] * w7[(66 + k) * 128 + j];
        }
        Wh[idx] = acc;
    }
    for (int j = t; j < 128; j += 256) {
        float acc = b7[j];
        for (int k = 0; k < 32; k++) acc += bb[k] * w7[(66 + k) * 128 + j];
        bh[j] = acc;
    }
    if (t == 0) {
        float s1 = 0.f, s2 = 0.f;
        for (int d = 0; d < 128; d++) { s1 += mu[d]; s2 += sg[d]; }
        float mmu = s1 / 128.f, msg = s2 / 128.f;
        float ss = 0.f;
        for (int d = 0; d < 128; d++) { float e = sg[d] - msg; ss += e * e; }
        stats[0] = mmu;
        stats[1] = sqrtf(64.f * ss / 8191.f);
    }
    __syncthreads();
    for (int idx = t; idx < 128 * 96; idx += 256) {
        int col = idx / 96, k = idx - col * 96;
        float v = (k < 66) ? Wh[k * 128 + col] : 0.f;
        whiT[idx] = (u16)bfr1(v);
    }
    float mean = stats[0], sd = stats[1];
    for (int p = t; p < 8192; p += 256) {
        u32 o0, o1;
        threefry42(0u, (u32)p, o0, o1);
        slots[p] = fmaf(sd, bits_to_normal(o0 ^ o1), mean);
    }
}

// ---------- K2: single-bf16 MFMA build of hln ----------

__global__ __launch_bounds__(256) void k2_hln(
    const float* __restrict__ inputs, const float* __restrict__ embed,
    const u16* __restrict__ whiT, const float* __restrict__ bh,
    const float* __restrict__ g, const float* __restrict__ bbias,
    u16* __restrict__ hlnb) {
    __shared__ __align__(16) char smem[34816];  // ebuf u16[128][104] / T u16[128][136]
    __shared__ float bhl[128], gl[128], bl[128];
    int t = threadIdx.x;
    u16* ebuf = (u16*)smem;
    size_t rbase = (size_t)blockIdx.x * 128;
    for (int idx = t; idx < 384; idx += 256)
        ebuf[(idx / 3) * 104 + (idx % 3)] = (u16)bfr1(inputs[rbase * 3 + idx]);
    for (int idx = t; idx < 128 * 63; idx += 256) {
        int r = idx / 63, i = idx - r * 63;
        ebuf[r * 104 + 3 + i] = (u16)bfr1(embed[rbase * 63 + idx]);
    }
    for (int idx = t; idx < 128 * 30; idx += 256) {
        int r = idx / 30, i = idx - r * 30;
        ebuf[r * 104 + 66 + i] = 0;
    }
    if (t < 128) { bhl[t] = bh[t]; gl[t] = g[t]; bl[t] = bbias[t]; }
    __syncthreads();

    int w = t >> 6, l = t & 63;
    int c16 = l & 15, g4 = l >> 4;
    int wr0 = w * 32;
    float bhc[8], gc[8], bc[8];
#pragma unroll
    for (int nt = 0; nt < 8; nt++) {
        bhc[nt] = bhl[nt * 16 + c16];
        gc[nt] = gl[nt * 16 + c16];
        bc[nt] = bl[nt * 16 + c16];
    }
    f32x4 acc[2][8];
#pragma unroll
    for (int mi = 0; mi < 2; mi++)
#pragma unroll
        for (int nt = 0; nt < 8; nt++)
            acc[mi][nt] = (f32x4){bhc[nt], bhc[nt], bhc[nt], bhc[nt]};

#pragma unroll
    for (int kc = 0; kc < 3; kc++) {
        bf16x8 a0 = *(const bf16x8*)&ebuf[(wr0 + c16) * 104 + kc * 32 + g4 * 8];
        bf16x8 a1 = *(const bf16x8*)&ebuf[(wr0 + 16 + c16) * 104 + kc * 32 + g4 * 8];
#pragma unroll
        for (int nt = 0; nt < 8; nt++) {
            uint4 bw = *(const uint4*)(whiT + (size_t)(nt * 16 + c16) * 96 + kc * 32 + g4 * 8);
            bf16x8 bf = *(bf16x8*)&bw;
            acc[0][nt] = __builtin_amdgcn_mfma_f32_16x16x32_bf16(a0, bf, acc[0][nt], 0, 0, 0);
            acc[1][nt] = __builtin_amdgcn_mfma_f32_16x16x32_bf16(a1, bf, acc[1][nt], 0, 0, 0);
        }
    }

    __syncthreads();
    u16* T = (u16*)smem;           // [128][136]
#pragma unroll
    for (int mi = 0; mi < 2; mi++) {
#pragma unroll
        for (int i = 0; i < 4; i++) {
            float s = 0.f;
#pragma unroll
            for (int nt = 0; nt < 8; nt++) s += acc[mi][nt][i];
            s += __shfl_xor(s, 1); s += __shfl_xor(s, 2);
            s += __shfl_xor(s, 4); s += __shfl_xor(s, 8);
            float m = s * (1.0f / 128.0f);
            float v = 0.f;
#pragma unroll
            for (int nt = 0; nt < 8; nt++) { float d = acc[mi][nt][i] - m; v = fmaf(d, d, v); }
            v += __shfl_xor(v, 1); v += __shfl_xor(v, 2);
            v += __shfl_xor(v, 4); v += __shfl_xor(v, 8);
            float inv = rsqrtf(v * (1.0f / 128.0f) + 1e-5f);
            int row = wr0 + mi * 16 + g4 * 4 + i;
#pragma unroll
            for (int nt = 0; nt < 8; nt++) {
                float val = fmaf((acc[mi][nt][i] - m) * inv, gc[nt], bc[nt]);
                T[row * 136 + nt * 16 + c16] = (u16)bfr1(val);
            }
        }
    }
    __syncthreads();
    {
        int r = t >> 1, hf = t & 1;
        const u16* Tr = T + r * 136 + hf * 64;
        u16* dst = hlnb + (rbase + r) * 128 + hf * 64;
#pragma unroll
        for (int j = 0; j < 8; j++) {
            uint4 v = *(const uint4*)(Tr + j * 8);
            *(uint4*)(dst + j * 8) = v;
        }
    }
}

// ---------- K3: initial q from slots ----------

__global__ __launch_bounds__(128) void k3_q(
    const float* __restrict__ slots,
    const float* __restrict__ lnsg, const float* __restrict__ lnsb,
    const float* __restrict__ wq, const float* __restrict__ bq,
    const float* __restrict__ wkT, const float* __restrict__ bk,
    float* __restrict__ qt, float* __restrict__ qc) {
    __shared__ float shA[128];
    __shared__ float red[2];
    int bs = blockIdx.x;
    float x = slots[bs * 128 + threadIdx.x];
    emit_q(x, bs, lnsg, lnsb, wq, bq, wkT, bk, qt, qc, shA, red);
}

// ---------- K4: MFMA attention, 2 pipelined tiles/wave ----------
// Tile: tw[d*32 + (r ^ (((d>>1)&3)<<3))], d=dim 0..127, r=row 0..31.
// LDS = 32768 + 5120 + 128 = 38016 B -> 4 blocks/CU.
// Phase-2 B-frag: single 16B-aligned ds_read_b128 per nt.

__global__ __launch_bounds__(256) void k4_attn(
    const uint4* __restrict__ hlnb4,
    const float* __restrict__ qt, const float* __restrict__ qc,
    float* __restrict__ vecp, float* __restrict__ denp) {
    __shared__ __align__(16) u16 tiles[4][128 * 32];   // 32768 B (vlds aliased)
    __shared__ __align__(16) u16 attnP[4][16 * 40];    // 5120 B
    __shared__ float dlds[4][8];
    int t = threadIdx.x;
    int w = t >> 6, l = t & 63;
    int blk = blockIdx.x;
    int b = blk >> 7, slab = blk & 127;
    size_t row0 = (size_t)b * N_ + (size_t)slab * 256 + (size_t)w * 32;
    int c16 = l & 15, g = l >> 4;
    u16* tw = tiles[w];

    bf16x8 qf[4];
#pragma unroll
    for (int kc = 0; kc < 4; kc++) {
        uint4 qu = {0u, 0u, 0u, 0u};
        if (c16 < 8) {
            const float* qp = qt + b * 1024 + c16 * 128 + kc * 32 + g * 8;
            float4 qa = *(const float4*)qp;
            float4 qb = *(const float4*)(qp + 4);
            qu.x = bfpack2(bfr1(qa.x), bfr1(qa.y));
            qu.y = bfpack2(bfr1(qa.z), bfr1(qa.w));
            qu.z = bfpack2(bfr1(qb.x), bfr1(qb.y));
            qu.w = bfpack2(bfr1(qb.z), bfr1(qb.w));
        }
        qf[kc] = *(bf16x8*)&qu;
    }
    float qcv = (c16 < 8) ? qc[b * 8 + c16] : 0.f;

    f32x4 uacc[8];
#pragma unroll
    for (int nt = 0; nt < 8; nt++) uacc[nt] = (f32x4){0.f, 0.f, 0.f, 0.f};
    float denacc = 0.f;

    uint4 st[8];
#pragma unroll
    for (int mt = 0; mt < 2; mt++)
#pragma unroll
        for (int kc = 0; kc < 4; kc++)
            st[mt * 4 + kc] = hlnb4[(row0 + mt * 16 + c16) * 16 + kc * 4 + g];

    for (int tt = 0; tt < 2; tt++) {
        f32x4 dacc[2];
        dacc[0] = (f32x4){0.f, 0.f, 0.f, 0.f};
        dacc[1] = (f32x4){0.f, 0.f, 0.f, 0.f};
#pragma unroll
        for (int mt = 0; mt < 2; mt++) {
#pragma unroll
            for (int kc = 0; kc < 4; kc++) {
                uint4 au = st[mt * 4 + kc];
                dacc[mt] = __builtin_amdgcn_mfma_f32_16x16x32_bf16(*(bf16x8*)&au, qf[kc], dacc[mt], 0, 0, 0);
                int r = mt * 16 + c16;
                int d0 = kc * 32 + g * 8;
#pragma unroll
                for (int k = 0; k < 8; k++) {
                    int d = d0 + k;
                    u32 word = (k & 1) ? 0u : 0u;  // placeholder, replaced below
                    (void)word;
                }
                // scalar u16 stores with XOR row swizzle
                {
                    int d;
                    d = d0 + 0; tw[d * 32 + (r ^ (((d >> 1) & 3) << 3))] = (u16)(au.x & 0xFFFF);
                    d = d0 + 1; tw[d * 32 + (r ^ (((d >> 1) & 3) << 3))] = (u16)(au.x >> 16);
                    d = d0 + 2; tw[d * 32 + (r ^ (((d >> 1) & 3) << 3))] = (u16)(au.y & 0xFFFF);
                    d = d0 + 3; tw[d * 32 + (r ^ (((d >> 1) & 3) << 3))] = (u16)(au.y >> 16);
                    d = d0 + 4; tw[d * 32 + (r ^ (((d >> 1) & 3) << 3))] = (u16)(au.z & 0xFFFF);
                    d = d0 + 5; tw[d * 32 + (r ^ (((d >> 1) & 3) << 3))] = (u16)(au.z >> 16);
                    d = d0 + 6; tw[d * 32 + (r ^ (((d >> 1) & 3) << 3))] = (u16)(au.w & 0xFFFF);
                    d = d0 + 7; tw[d * 32 + (r ^ (((d >> 1) & 3) << 3))] = (u16)(au.w >> 16);
                }
            }
        }
        if (tt == 0) {
            size_t rowB = row0 + 128;
#pragma unroll
            for (int mt = 0; mt < 2; mt++)
#pragma unroll
                for (int kc = 0; kc < 4; kc++)
                    st[mt * 4 + kc] = hlnb4[(rowB + mt * 16 + c16) * 16 + kc * 4 + g];
        }
#pragma unroll
        for (int mt = 0; mt < 2; mt++) {
            float pv[4];
#pragma unroll
            for (int r = 0; r < 4; r++) {
                float v = dacc[mt][r] + qcv;
                float mx = v;
                mx = fmaxf(mx, __shfl_xor(mx, 1));
                mx = fmaxf(mx, __shfl_xor(mx, 2));
                mx = fmaxf(mx, __shfl_xor(mx, 4));
                float e = __expf(v - mx);
                float ssum = e;
                ssum += __shfl_xor(ssum, 1);
                ssum += __shfl_xor(ssum, 2);
                ssum += __shfl_xor(ssum, 4);
                float a = (c16 < 8) ? fmaf(e, 1.0f / ssum, 1e-8f) : 0.f;
                pv[r] = a;
                denacc += a;
            }
            uint2 pw;
            pw.x = bfpack2(bfr1(pv[0]), bfr1(pv[1]));
            pw.y = bfpack2(bfr1(pv[2]), bfr1(pv[3]));
            *(uint2*)&attnP[w][c16 * 40 + mt * 16 + g * 4] = pw;
        }
        uint4 afu = *(const uint4*)&attnP[w][c16 * 40 + g * 8];
        bf16x8 af = *(bf16x8*)&afu;
#pragma unroll
        for (int nt = 0; nt < 8; nt++) {
            int d = nt * 16 + c16;
            int rb = (g * 8) ^ (((d >> 1) & 3) << 3);
            uint4 bu = *(const uint4*)(tw + d * 32 + rb);
            uacc[nt] = __builtin_amdgcn_mfma_f32_16x16x32_bf16(af, *(bf16x8*)&bu, uacc[nt], 0, 0, 0);
        }
    }
    denacc += __shfl_xor(denacc, 16);
    denacc += __shfl_xor(denacc, 32);
    if (l < 8) dlds[w][l] = denacc;

    __syncthreads();
    float* vlds0 = (float*)&tiles[0][0];
    float* vlds1 = vlds0 + 1024;
    if (w < 2 && g < 2) {
        float* vb = (w == 0) ? vlds0 : vlds1;
#pragma unroll
        for (int nt = 0; nt < 8; nt++)
#pragma unroll
            for (int r = 0; r < 4; r++)
                vb[(g * 4 + r) * 128 + nt * 16 + c16] = uacc[nt][r];
    }
    __syncthreads();
    if (w >= 2 && g < 2) {
        float* vb = (w == 2) ? vlds0 : vlds1;
#pragma unroll
        for (int nt = 0; nt < 8; nt++)
#pragma unroll
            for (int r = 0; r < 4; r++)
                vb[(g * 4 + r) * 128 + nt * 16 + c16] += uacc[nt][r];
    }
    __syncthreads();
    float* vout = vecp + ((size_t)blk << 10);
#pragma unroll
    for (int rep = 0; rep < 4; rep++) {
        int o = rep * 256 + t;
        vout[o] = vlds0[o] + vlds1[o];
    }
    if (t < 8) denp[blk * 8 + t] = dlds[0][t] + dlds[1][t] + dlds[2][t] + dlds[3][t];
}

// ---------- K5: 512-thread parallel update ----------

__device__ inline float sum512(float v, float* red8) {
#pragma unroll
    for (int o = 32; o; o >>= 1) v += __shfl_down(v, o);
    __syncthreads();
    if ((threadIdx.x & 63) == 0) red8[threadIdx.x >> 6] = v;
    __syncthreads();
    float s = 0.f;
#pragma unroll
    for (int i = 0; i < 8; i++) s += red8[i];
    return s;
}

__device__ inline float reduce4(float part, float* praw, int qq, int d) {
    __syncthreads();
    praw[qq * 128 + d] = part;
    __syncthreads();
    return praw[d] + praw[128 + d] + praw[256 + d] + praw[384 + d];
}

__global__ __launch_bounds__(512) void k5_update(
    const float* __restrict__ vecp, const float* __restrict__ denp,
    const float* __restrict__ wv, const float* __restrict__ bv,
    const float* __restrict__ wihT, const float* __restrict__ whhT,
    const float* __restrict__ bih, const float* __restrict__ bhh,
    const float* __restrict__ lnfg, const float* __restrict__ lnfb,
    const float* __restrict__ m1w, const float* __restrict__ m1b,
    const float* __restrict__ m2w, const float* __restrict__ m2b,
    float* __restrict__ slots,
    const float* __restrict__ lnsg, const float* __restrict__ lnsb,
    const float* __restrict__ wq, const float* __restrict__ bq,
    const float* __restrict__ wkT, const float* __restrict__ bk,
    float* __restrict__ qt, float* __restrict__ qc,
    float* __restrict__ out, int compute_q, int write_out) {
    __shared__ float sA[128], sB[128], sC[128], sH[128], sQ[128];
    __shared__ float praw[512];
    __shared__ float red8[8];
    __shared__ float gsc[6][512];
    int t = threadIdx.x;
    int bs = blockIdx.x;
    int b = bs >> 3, slot = bs & 7;
    int d = t & 127, qq = t >> 7;

    float dvp = (t < 128) ? denp[((size_t)(b * 128) + t) * 8 + slot] : 0.f;
    float dv = sum512(dvp, red8);

    float vs = 0.f;
    const float* vp0 = vecp + (((size_t)(b * 128 + qq * 32)) << 10) + slot * 128 + d;
#pragma unroll 8
    for (int s = 0; s < 32; s++) vs += vp0[(size_t)s << 10];
    float vtot = reduce4(vs, praw, qq, d);
    if (qq == 0) { sA[d] = vtot / dv; sC[d] = slots[bs * 128 + d]; }
    __syncthreads();

    float up = 0.f;
    {
        const float* wvp = wv + (size_t)(qq * 32) * 128 + d;
#pragma unroll 8
        for (int i = 0; i < 32; i++) up = fmaf(sA[qq * 32 + i], wvp[i * 128], up);
    }
    float updt = reduce4(up, praw, qq, d) + bv[d];
    if (qq == 0) sB[d] = updt;
    __syncthreads();

#pragma unroll 1
    for (int gx = 0; gx < 3; gx++) {
        int g = gx * 128 + d;
        float ap = 0.f, hp = 0.f;
        const float* wi = wihT + (size_t)(qq * 32) * 384 + g;
        const float* wh = whhT + (size_t)(qq * 32) * 384 + g;
#pragma unroll 8
        for (int i = 0; i < 32; i++) {
            ap = fmaf(sB[qq * 32 + i], wi[i * 384], ap);
            hp = fmaf(sC[qq * 32 + i], wh[i * 384], hp);
        }
        gsc[gx * 2][t] = ap;
        gsc[gx * 2 + 1][t] = hp;
    }
    __syncthreads();
    float gi0 = gsc[0][d] + gsc[0][128 + d] + gsc[0][256 + d] + gsc[0][384 + d] + bih[d];
    float gh0 = gsc[1][d] + gsc[1][128 + d] + gsc[1][256 + d] + gsc[1][384 + d] + bhh[d];
    float gi1 = gsc[2][d] + gsc[2][128 + d] + gsc[2][256 + d] + gsc[2][384 + d] + bih[128 + d];
    float gh1 = gsc[3][d] + gsc[3][128 + d] + gsc[3][256 + d] + gsc[3][384 + d] + bhh[128 + d];
    float gi2 = gsc[4][d] + gsc[4][128 + d] + gsc[4][256 + d] + gsc[4][384 + d] + bih[256 + d];
    float gh2 = gsc[5][d] + gsc[5][128 + d] + gsc[5][256 + d] + gsc[5][384 + d] + bhh[256 + d];
    float rg = 1.f / (1.f + expf(-(gi0 + gh0)));
    float zg = 1.f / (1.f + expf(-(gi1 + gh1)));
    float ng = tanhf(fmaf(rg, gh2, gi2));
    float hnew = (1.f - zg) * ng + zg * sC[d];
    __syncthreads();
    if (qq == 0) sH[d] = hnew;
    __syncthreads();

    float xh = (t < 128) ? sH[t] : 0.f;
    float mh = sum512(xh, red8) * (1.0f / 128.0f);
    float eh = xh - mh;
    float vh = sum512((t < 128) ? eh * eh : 0.f, red8) * (1.0f / 128.0f);
    float invh = rsqrtf(vh + 1e-5f);
    __syncthreads();
    if (t < 128) sA[t] = fmaf(eh * invh, lnfg[t], lnfb[t]);
    __syncthreads();

    float p1 = 0.f;
    {
        const float* m1p = m1w + (size_t)(qq * 32) * 128 + d;
#pragma unroll 8
        for (int i = 0; i < 32; i++) p1 = fmaf(sA[qq * 32 + i], m1p[i * 128], p1);
    }
    float m1v = reduce4(p1, praw, qq, d) + m1b[d];
    if (qq == 0) sB[d] = m1v;
    __syncthreads();

    float p2 = 0.f;
    {
        const float* m2p = m2w + (size_t)(qq * 32) * 128 + d;
#pragma unroll 8
        for (int i = 0; i < 32; i++) p2 = fmaf(sB[qq * 32 + i], m2p[i * 128], p2);
    }
    float m2v = reduce4(p2, praw, qq, d) + m2b[d];
    float snew = sH[d] + m2v;
    __syncthreads();
    if (qq == 0) {
        slots[bs * 128 + d] = snew;
        if (write_out) out[bs * 128 + d] = snew;
        sH[d] = snew;
    }
    __syncthreads();

    if (compute_q) {
        float xs = (t < 128) ? sH[t] : 0.f;
        float ms = sum512(xs, red8) * (1.0f / 128.0f);
        float es = xs - ms;
        float vs2 = sum512((t < 128) ? es * es : 0.f, red8) * (1.0f / 128.0f);
        float invs = rsqrtf(vs2 + 1e-5f);
        __syncthreads();
        if (t < 128) sA[t] = fmaf(es * invs, lnsg[t], lnsb[t]);
        __syncthreads();
        float pq = 0.f;
        {
            const float* wqp = wq + (size_t)(qq * 32) * 128 + d;
#pragma unroll 8
            for (int i = 0; i < 32; i++) pq = fmaf(sA[qq * 32 + i], wqp[i * 128], pq);
        }
        float qv = reduce4(pq, praw, qq, d) + bq[d];
        if (qq == 0) sQ[d] = qv;
        __syncthreads();
        float pa = 0.f;
        {
            const float* wkp = wkT + (size_t)(qq * 32) * 128 + d;
#pragma unroll 8
            for (int j = 0; j < 32; j++) pa = fmaf(wkp[j * 128], sQ[qq * 32 + j], pa);
        }
        const float scale = 0.08838834764831845f;
        float a2 = reduce4(pa, praw, qq, d) * scale;
        if (qq == 0) qt[bs * 128 + d] = a2;
        float xpr = (t < 128) ? sQ[t] * bk[t] : 0.f;
        float pr = sum512(xpr, red8);
        if (t == 0) qc[bs] = pr * scale;
    }
}

// ---------- launch ----------

extern "C" void kernel_launch(void* const* d_in, const int* in_sizes, int n_in,
                              void* d_out, int out_size, void* d_ws, size_t ws_size,
                              hipStream_t stream) {
    const float* inputs = (const float*)d_in[0];
    const float* embed  = (const float*)d_in[1];
    const float* mu     = (const float*)d_in[2];
    const float* sg     = (const float*)d_in[3];
    const float* w0 = (const float*)d_in[4];  const float* b0 = (const float*)d_in[5];
    const float* w1 = (const float*)d_in[6];  const float* b1 = (const float*)d_in[7];
    const float* w2 = (const float*)d_in[8];  const float* b2 = (const float*)d_in[9];
    const float* w3 = (const float*)d_in[10]; const float* b3 = (const float*)d_in[11];
    const float* w4 = (const float*)d_in[12]; const float* b4 = (const float*)d_in[13];
    const float* w5 = (const float*)d_in[14]; const float* b5 = (const float*)d_in[15];
    const float* w7 = (const float*)d_in[16]; const float* b7 = (const float*)d_in[17];
    const float* wq = (const float*)d_in[18]; const float* bq = (const float*)d_in[19];
    const float* wk = (const float*)d_in[20]; const float* bk = (const float*)d_in[21];
    const float* wv = (const float*)d_in[22]; const float* bv = (const float*)d_in[23];
    const float* ln_in_g = (const float*)d_in[24]; const float* ln_in_b = (const float*)d_in[25];
    const float* ln_sl_g = (const float*)d_in[26]; const float* ln_sl_b = (const float*)d_in[27];
    const float* ln_ff_g = (const float*)d_in[28]; const float* ln_ff_b = (const float*)d_in[29];
    const float* gwih = (const float*)d_in[30]; const float* gwhh = (const float*)d_in[31];
    const float* gbih = (const float*)d_in[32]; const float* gbhh = (const float*)d_in[33];
    const float* m1w = (const float*)d_in[34]; const float* m1b = (const float*)d_in[35];
    const float* m2w = (const float*)d_in[36]; const float* m2b = (const float*)d_in[37];

    char* ws = (char*)d_ws;
    u16* hlnb = (u16*)ws;
    size_t off = (size_t)NB_ * 128 * 2;  // 64 MB bf16 hln row-major
    float* Wh    = (float*)(ws + off); off += 66 * 128 * 4;
    float* bh    = (float*)(ws + off); off += 128 * 4;
    float* slots = (float*)(ws + off); off += 64 * 128 * 4;
    float* qt    = (float*)(ws + off); off += 64 * 128 * 4;
    float* qc    = (float*)(ws + off); off += 64 * 4;
    float* vecp  = (float*)(ws + off); off += (size_t)1024 * 1024 * 4;  // 4 MB
    float* denp  = (float*)(ws + off); off += 1024 * 8 * 4;
    float* wihT  = (float*)(ws + off); off += 384 * 128 * 4;
    float* whhT  = (float*)(ws + off); off += 384 * 128 * 4;
    float* wkT   = (float*)(ws + off); off += 128 * 128 * 4;
    u16* whiT    = (u16*)(ws + off); off += 128 * 96 * 2;

    k0_transpose<<<448, 256, 0, stream>>>(gwih, gwhh, wk, wihT, whhT, wkT);
    k1_setup<<<1, 256, 0, stream>>>(w0, b0, w1, b1, w2, b2, w3, b3, w4, b4, w5, b5,
                                    w7, b7, mu, sg, Wh, bh, slots, whiT);
    k2_hln<<<NB_ / 128, 256, 0, stream>>>(inputs, embed, whiT, bh,
                                          ln_in_g, ln_in_b, hlnb);
    k3_q<<<64, 128, 0, stream>>>(slots, ln_sl_g, ln_sl_b, wq, bq, wkT, bk, qt, qc);
    for (int it = 0; it < 3; it++) {
        k4_attn<<<1024, 256, 0, stream>>>((const uint4*)hlnb, qt, qc, vecp, denp);
        k5_update<<<64, 512, 0, stream>>>(vecp, denp, wv, bv, wihT, whhT, gbih, gbhh,
                                          ln_ff_g, ln_ff_b, m1w, m1b, m2w, m2b, slots,
                                          ln_sl_g, ln_sl_b, wq, bq, wkT, bk, qt, qc,
                                          (float*)d_out, (it < 2) ? 1 : 0, (it == 2) ? 1 : 0);
    }
}

// Round 23
// 253.806 us; speedup vs baseline: 1.1485x; 1.0160x over previous
//
#include <hip/hip_runtime.h>

// SlotAttention (bf16 hln, single layout, MFMA). Round-22 structure +
// k4 __launch_bounds__(256,4): cap VGPR at 128 -> 4 blocks/CU residency.
//   - 6-layer linear stack folded into 66->128 affine (Wh, bh).
//   - k,v folded out of N.
//   - hln bf16 row-major [NB][128] (64 MB, L3-resident).
//   - k2: single-bf16 MFMA GEMM; E pre-converted bf16 in LDS.
//   - k4 x3: 1024 blocks x 4 waves x 2 pipelined 32-row tiles; stride-32
//     XOR-swizzled transposed tile; per-slab partials (no atomics).
//   - k5: 512 threads; GEMVs as 32-iter partials + LDS tree reduce.

#define B_  8
#define N_  32768
#define NB_ (B_ * N_)
#define D_  128
#define S_  8

typedef unsigned int u32;
typedef unsigned short u16;
typedef __attribute__((ext_vector_type(8))) short bf16x8;
typedef __attribute__((ext_vector_type(4))) float f32x4;

__device__ inline u32 bfr1(float x) {  // f32 -> bf16 (RNE)
    u32 u = __float_as_uint(x);
    return (u + 0x7FFFu + ((u >> 16) & 1u)) >> 16;
}
__device__ inline u32 bfpack2(u32 lo, u32 hi) { return lo | (hi << 16); }

// threefry2x32, key = (0, 42)
__device__ inline void threefry42(u32 c0, u32 c1, u32& o0, u32& o1) {
    const u32 k0 = 0u, k1 = 42u, k2 = 0x1BD11BDAu ^ 0u ^ 42u;
    const u32 ks[3] = {k0, k1, k2};
    u32 x0 = c0 + k0, x1 = c1 + k1;
    const int rA[4] = {13, 15, 26, 6}, rB[4] = {17, 29, 16, 24};
#pragma unroll
    for (int i = 0; i < 5; i++) {
#pragma unroll
        for (int k = 0; k < 4; k++) {
            int r = (i & 1) ? rB[k] : rA[k];
            x0 += x1;
            x1 = (x1 << r) | (x1 >> (32 - r));
            x1 ^= x0;
        }
        x0 += ks[(i + 1) % 3];
        x1 += ks[(i + 2) % 3] + (u32)(i + 1);
    }
    o0 = x0; o1 = x1;
}

// jax uniform(-0.99999994, 1) -> sqrt(2)*erfinv
__device__ inline float bits_to_normal(u32 b) {
    float f = __uint_as_float((b >> 9) | 0x3f800000u) - 1.0f;
    const float lo = -0.99999994f;
    float r = fmaxf(lo, f * 1.99999994f + lo);
    float w = -log1pf(-r * r);
    float p;
    if (w < 5.0f) {
        w -= 2.5f;
        p = 2.81022636e-08f;
        p = fmaf(p, w, 3.43273939e-07f);
        p = fmaf(p, w, -3.5233877e-06f);
        p = fmaf(p, w, -4.39150654e-06f);
        p = fmaf(p, w, 0.00021858087f);
        p = fmaf(p, w, -0.00125372503f);
        p = fmaf(p, w, -0.00417768164f);
        p = fmaf(p, w, 0.246640727f);
        p = fmaf(p, w, 1.50140941f);
    } else {
        w = sqrtf(w) - 3.0f;
        p = -0.000200214257f;
        p = fmaf(p, w, 0.000100950558f);
        p = fmaf(p, w, 0.00134934322f);
        p = fmaf(p, w, -0.00367342844f);
        p = fmaf(p, w, 0.00573950773f);
        p = fmaf(p, w, -0.0076224613f);
        p = fmaf(p, w, 0.00943887047f);
        p = fmaf(p, w, 1.00167406f);
        p = fmaf(p, w, 2.83297682f);
    }
    return 1.41421356f * (p * r);
}

// 128-thread block sum (k3 only)
__device__ inline float block128_sum(float v, float* red) {
#pragma unroll
    for (int o = 32; o; o >>= 1) v += __shfl_down(v, o);
    __syncthreads();
    if ((threadIdx.x & 63) == 0) red[threadIdx.x >> 6] = v;
    __syncthreads();
    return red[0] + red[1];
}

// emit_q for 128-thread k3
__device__ void emit_q(float x, int bs,
                       const float* lnsg, const float* lnsb,
                       const float* wq, const float* bq,
                       const float* wkT, const float* bk,
                       float* qt, float* qc,
                       float* shA, float* red) {
    int t = threadIdx.x;
    float m = block128_sum(x, red) * (1.0f / 128.0f);
    float e = x - m;
    float var = block128_sum(e * e, red) * (1.0f / 128.0f);
    float inv = rsqrtf(var + 1e-5f);
    __syncthreads();
    shA[t] = fmaf(e * inv, lnsg[t], lnsb[t]);
    __syncthreads();
    float q = bq[t];
#pragma unroll 4
    for (int i = 0; i < 128; i++) q = fmaf(shA[i], wq[i * 128 + t], q);
    __syncthreads();
    shA[t] = q;
    __syncthreads();
    float a2 = 0.f;
#pragma unroll 4
    for (int j = 0; j < 128; j++) a2 = fmaf(wkT[j * 128 + t], shA[j], a2);
    const float scale = 0.08838834764831845f;  // 128^-0.5
    qt[bs * 128 + t] = a2 * scale;
    float pr = block128_sum(shA[t] * bk[t], red);
    if (t == 0) qc[bs] = pr * scale;
}

// ---------- K0: transpose gru weights + wk ----------

__global__ __launch_bounds__(256) void k0_transpose(
    const float* __restrict__ wih, const float* __restrict__ whh,
    const float* __restrict__ wk,
    float* __restrict__ wihT, float* __restrict__ whhT, float* __restrict__ wkT) {
    int idx = blockIdx.x * 256 + threadIdx.x;
    if (idx < 49152) {
        int d = idx / 384, g = idx % 384;
        wihT[idx] = wih[g * 128 + d];
    } else if (idx < 98304) {
        int o = idx - 49152;
        int d = o / 384, g = o % 384;
        whhT[o] = whh[g * 128 + d];
    } else if (idx < 114688) {
        int o = idx - 98304;
        int j = o >> 7, tcol = o & 127;
        wkT[o] = wk[tcol * 128 + j];
    }
}

// ---------- K1: fold weights, init slots, bf16 W ----------

__global__ __launch_bounds__(256) void k1_setup(
    const float* __restrict__ w0, const float* __restrict__ b0,
    const float* __restrict__ w1, const float* __restrict__ b1,
    const float* __restrict__ w2, const float* __restrict__ b2,
    const float* __restrict__ w3, const float* __restrict__ b3,
    const float* __restrict__ w4, const float* __restrict__ b4,
    const float* __restrict__ w5, const float* __restrict__ b5,
    const float* __restrict__ w7, const float* __restrict__ b7,
    const float* __restrict__ mu, const float* __restrict__ sg,
    float* __restrict__ Wh, float* __restrict__ bh, float* __restrict__ slots,
    u16* __restrict__ whiT) {
    __shared__ float A[192], Bt[96], bb[64], bb2[32];
    __shared__ float stats[2];
    int t = threadIdx.x;
    for (int i = t; i < 192; i += 256) A[i] = w0[i];
    for (int i = t; i < 64; i += 256) bb[i] = b0[i];
    __syncthreads();
    const float* wl[5] = {w1, w2, w3, w4, w5};
    const float* bl[5] = {b1, b2, b3, b4, b5};
    int kin = 64;
    for (int l = 0; l < 5; l++) {
        const float* w = wl[l];
        const float* bias = bl[l];
        if (t < 96) {
            int i = t / 32, j = t % 32;
            float acc = 0.f;
            for (int k = 0; k < kin; k++) acc += A[i * kin + k] * w[k * 32 + j];
            Bt[i * 32 + j] = acc;
        } else if (t < 128) {
            int j = t - 96;
            float acc = bias[j];
            for (int k = 0; k < kin; k++) acc += bb[k] * w[k * 32 + j];
            bb2[j] = acc;
        }
        __syncthreads();
        if (t < 96) A[t] = Bt[t];
        if (t < 32) bb[t] = bb2[t];
        __syncthreads();
        kin = 32;
    }
    for (int idx = t; idx < 66 * 128; idx += 256) {
        int i = idx >> 7, j = idx & 127;
        float acc = w7[idx];
        if (i < 3) {
            for (int k = 0; k < 32; k++) acc += A[i * 32 + k] * w7[(66 + k) * 128 + j];
        }
        Wh[idx] = acc;
    }
    for (int j = t; j < 128; j += 256) {
        float acc = b7[j];
        for (int k = 0; k < 32; k++) acc += bb[k] * w7[(66 + k) * 128 + j];
        bh[j] = acc;
    }
    if (t == 0) {
        float s1 = 0.f, s2 = 0.f;
        for (int d = 0; d < 128; d++) { s1 += mu[d]; s2 += sg[d]; }
        float mmu = s1 / 128.f, msg = s2 / 128.f;
        float ss = 0.f;
        for (int d = 0; d < 128; d++) { float e = sg[d] - msg; ss += e * e; }
        stats[0] = mmu;
        stats[1] = sqrtf(64.f * ss / 8191.f);
    }
    __syncthreads();
    for (int idx = t; idx < 128 * 96; idx += 256) {
        int col = idx / 96, k = idx - col * 96;
        float v = (k < 66) ? Wh[k * 128 + col] : 0.f;
        whiT[idx] = (u16)bfr1(v);
    }
    float mean = stats[0], sd = stats[1];
    for (int p = t; p < 8192; p += 256) {
        u32 o0, o1;
        threefry42(0u, (u32)p, o0, o1);
        slots[p] = fmaf(sd, bits_to_normal(o0 ^ o1), mean);
    }
}

// ---------- K2: single-bf16 MFMA build of hln ----------

__global__ __launch_bounds__(256) void k2_hln(
    const float* __restrict__ inputs, const float* __restrict__ embed,
    const u16* __restrict__ whiT, const float* __restrict__ bh,
    const float* __restrict__ g, const float* __restrict__ bbias,
    u16* __restrict__ hlnb) {
    __shared__ __align__(16) char smem[34816];  // ebuf u16[128][104] / T u16[128][136]
    __shared__ float bhl[128], gl[128], bl[128];
    int t = threadIdx.x;
    u16* ebuf = (u16*)smem;
    size_t rbase = (size_t)blockIdx.x * 128;
    for (int idx = t; idx < 384; idx += 256)
        ebuf[(idx / 3) * 104 + (idx % 3)] = (u16)bfr1(inputs[rbase * 3 + idx]);
    for (int idx = t; idx < 128 * 63; idx += 256) {
        int r = idx / 63, i = idx - r * 63;
        ebuf[r * 104 + 3 + i] = (u16)bfr1(embed[rbase * 63 + idx]);
    }
    for (int idx = t; idx < 128 * 30; idx += 256) {
        int r = idx / 30, i = idx - r * 30;
        ebuf[r * 104 + 66 + i] = 0;
    }
    if (t < 128) { bhl[t] = bh[t]; gl[t] = g[t]; bl[t] = bbias[t]; }
    __syncthreads();

    int w = t >> 6, l = t & 63;
    int c16 = l & 15, g4 = l >> 4;
    int wr0 = w * 32;
    float bhc[8], gc[8], bc[8];
#pragma unroll
    for (int nt = 0; nt < 8; nt++) {
        bhc[nt] = bhl[nt * 16 + c16];
        gc[nt] = gl[nt * 16 + c16];
        bc[nt] = bl[nt * 16 + c16];
    }
    f32x4 acc[2][8];
#pragma unroll
    for (int mi = 0; mi < 2; mi++)
#pragma unroll
        for (int nt = 0; nt < 8; nt++)
            acc[mi][nt] = (f32x4){bhc[nt], bhc[nt], bhc[nt], bhc[nt]};

#pragma unroll
    for (int kc = 0; kc < 3; kc++) {
        bf16x8 a0 = *(const bf16x8*)&ebuf[(wr0 + c16) * 104 + kc * 32 + g4 * 8];
        bf16x8 a1 = *(const bf16x8*)&ebuf[(wr0 + 16 + c16) * 104 + kc * 32 + g4 * 8];
#pragma unroll
        for (int nt = 0; nt < 8; nt++) {
            uint4 bw = *(const uint4*)(whiT + (size_t)(nt * 16 + c16) * 96 + kc * 32 + g4 * 8);
            bf16x8 bf = *(bf16x8*)&bw;
            acc[0][nt] = __builtin_amdgcn_mfma_f32_16x16x32_bf16(a0, bf, acc[0][nt], 0, 0, 0);
            acc[1][nt] = __builtin_amdgcn_mfma_f32_16x16x32_bf16(a1, bf, acc[1][nt], 0, 0, 0);
        }
    }

    __syncthreads();
    u16* T = (u16*)smem;           // [128][136]
#pragma unroll
    for (int mi = 0; mi < 2; mi++) {
#pragma unroll
        for (int i = 0; i < 4; i++) {
            float s = 0.f;
#pragma unroll
            for (int nt = 0; nt < 8; nt++) s += acc[mi][nt][i];
            s += __shfl_xor(s, 1); s += __shfl_xor(s, 2);
            s += __shfl_xor(s, 4); s += __shfl_xor(s, 8);
            float m = s * (1.0f / 128.0f);
            float v = 0.f;
#pragma unroll
            for (int nt = 0; nt < 8; nt++) { float d = acc[mi][nt][i] - m; v = fmaf(d, d, v); }
            v += __shfl_xor(v, 1); v += __shfl_xor(v, 2);
            v += __shfl_xor(v, 4); v += __shfl_xor(v, 8);
            float inv = rsqrtf(v * (1.0f / 128.0f) + 1e-5f);
            int row = wr0 + mi * 16 + g4 * 4 + i;
#pragma unroll
            for (int nt = 0; nt < 8; nt++) {
                float val = fmaf((acc[mi][nt][i] - m) * inv, gc[nt], bc[nt]);
                T[row * 136 + nt * 16 + c16] = (u16)bfr1(val);
            }
        }
    }
    __syncthreads();
    {
        int r = t >> 1, hf = t & 1;
        const u16* Tr = T + r * 136 + hf * 64;
        u16* dst = hlnb + (rbase + r) * 128 + hf * 64;
#pragma unroll
        for (int j = 0; j < 8; j++) {
            uint4 v = *(const uint4*)(Tr + j * 8);
            *(uint4*)(dst + j * 8) = v;
        }
    }
}

// ---------- K3: initial q from slots ----------

__global__ __launch_bounds__(128) void k3_q(
    const float* __restrict__ slots,
    const float* __restrict__ lnsg, const float* __restrict__ lnsb,
    const float* __restrict__ wq, const float* __restrict__ bq,
    const float* __restrict__ wkT, const float* __restrict__ bk,
    float* __restrict__ qt, float* __restrict__ qc) {
    __shared__ float shA[128];
    __shared__ float red[2];
    int bs = blockIdx.x;
    float x = slots[bs * 128 + threadIdx.x];
    emit_q(x, bs, lnsg, lnsb, wq, bq, wkT, bk, qt, qc, shA, red);
}

// ---------- K4: MFMA attention, 2 pipelined tiles/wave ----------
// Tile: tw[d*32 + (r ^ (((d>>1)&3)<<3))]. LDS 38016 B. VGPR capped at 128
// via __launch_bounds__(256,4) -> 4 blocks/CU, all 1024 blocks resident.

__global__ __launch_bounds__(256, 4) void k4_attn(
    const uint4* __restrict__ hlnb4,
    const float* __restrict__ qt, const float* __restrict__ qc,
    float* __restrict__ vecp, float* __restrict__ denp) {
    __shared__ __align__(16) u16 tiles[4][128 * 32];   // 32768 B (vlds aliased)
    __shared__ __align__(16) u16 attnP[4][16 * 40];    // 5120 B
    __shared__ float dlds[4][8];
    int t = threadIdx.x;
    int w = t >> 6, l = t & 63;
    int blk = blockIdx.x;
    int b = blk >> 7, slab = blk & 127;
    size_t row0 = (size_t)b * N_ + (size_t)slab * 256 + (size_t)w * 32;
    int c16 = l & 15, g = l >> 4;
    u16* tw = tiles[w];

    bf16x8 qf[4];
#pragma unroll
    for (int kc = 0; kc < 4; kc++) {
        uint4 qu = {0u, 0u, 0u, 0u};
        if (c16 < 8) {
            const float* qp = qt + b * 1024 + c16 * 128 + kc * 32 + g * 8;
            float4 qa = *(const float4*)qp;
            float4 qb = *(const float4*)(qp + 4);
            qu.x = bfpack2(bfr1(qa.x), bfr1(qa.y));
            qu.y = bfpack2(bfr1(qa.z), bfr1(qa.w));
            qu.z = bfpack2(bfr1(qb.x), bfr1(qb.y));
            qu.w = bfpack2(bfr1(qb.z), bfr1(qb.w));
        }
        qf[kc] = *(bf16x8*)&qu;
    }
    float qcv = (c16 < 8) ? qc[b * 8 + c16] : 0.f;

    f32x4 uacc[8];
#pragma unroll
    for (int nt = 0; nt < 8; nt++) uacc[nt] = (f32x4){0.f, 0.f, 0.f, 0.f};
    float denacc = 0.f;

    uint4 st[8];
#pragma unroll
    for (int mt = 0; mt < 2; mt++)
#pragma unroll
        for (int kc = 0; kc < 4; kc++)
            st[mt * 4 + kc] = hlnb4[(row0 + mt * 16 + c16) * 16 + kc * 4 + g];

    for (int tt = 0; tt < 2; tt++) {
        f32x4 dacc[2];
        dacc[0] = (f32x4){0.f, 0.f, 0.f, 0.f};
        dacc[1] = (f32x4){0.f, 0.f, 0.f, 0.f};
#pragma unroll
        for (int mt = 0; mt < 2; mt++) {
#pragma unroll
            for (int kc = 0; kc < 4; kc++) {
                uint4 au = st[mt * 4 + kc];
                dacc[mt] = __builtin_amdgcn_mfma_f32_16x16x32_bf16(*(bf16x8*)&au, qf[kc], dacc[mt], 0, 0, 0);
                int r = mt * 16 + c16;
                int d0 = kc * 32 + g * 8;
                int d;
                d = d0 + 0; tw[d * 32 + (r ^ (((d >> 1) & 3) << 3))] = (u16)(au.x & 0xFFFF);
                d = d0 + 1; tw[d * 32 + (r ^ (((d >> 1) & 3) << 3))] = (u16)(au.x >> 16);
                d = d0 + 2; tw[d * 32 + (r ^ (((d >> 1) & 3) << 3))] = (u16)(au.y & 0xFFFF);
                d = d0 + 3; tw[d * 32 + (r ^ (((d >> 1) & 3) << 3))] = (u16)(au.y >> 16);
                d = d0 + 4; tw[d * 32 + (r ^ (((d >> 1) & 3) << 3))] = (u16)(au.z & 0xFFFF);
                d = d0 + 5; tw[d * 32 + (r ^ (((d >> 1) & 3) << 3))] = (u16)(au.z >> 16);
                d = d0 + 6; tw[d * 32 + (r ^ (((d >> 1) & 3) << 3))] = (u16)(au.w & 0xFFFF);
                d = d0 + 7; tw[d * 32 + (r ^ (((d >> 1) & 3) << 3))] = (u16)(au.w >> 16);
            }
        }
        if (tt == 0) {
            size_t rowB = row0 + 128;
#pragma unroll
            for (int mt = 0; mt < 2; mt++)
#pragma unroll
                for (int kc = 0; kc < 4; kc++)
                    st[mt * 4 + kc] = hlnb4[(rowB + mt * 16 + c16) * 16 + kc * 4 + g];
        }
#pragma unroll
        for (int mt = 0; mt < 2; mt++) {
            float pv[4];
#pragma unroll
            for (int r = 0; r < 4; r++) {
                float v = dacc[mt][r] + qcv;
                float mx = v;
                mx = fmaxf(mx, __shfl_xor(mx, 1));
                mx = fmaxf(mx, __shfl_xor(mx, 2));
                mx = fmaxf(mx, __shfl_xor(mx, 4));
                float e = __expf(v - mx);
                float ssum = e;
                ssum += __shfl_xor(ssum, 1);
                ssum += __shfl_xor(ssum, 2);
                ssum += __shfl_xor(ssum, 4);
                float a = (c16 < 8) ? fmaf(e, 1.0f / ssum, 1e-8f) : 0.f;
                pv[r] = a;
                denacc += a;
            }
            uint2 pw;
            pw.x = bfpack2(bfr1(pv[0]), bfr1(pv[1]));
            pw.y = bfpack2(bfr1(pv[2]), bfr1(pv[3]));
            *(uint2*)&attnP[w][c16 * 40 + mt * 16 + g * 4] = pw;
        }
        uint4 afu = *(const uint4*)&attnP[w][c16 * 40 + g * 8];
        bf16x8 af = *(bf16x8*)&afu;
#pragma unroll
        for (int nt = 0; nt < 8; nt++) {
            int d = nt * 16 + c16;
            int rb = (g * 8) ^ (((d >> 1) & 3) << 3);
            uint4 bu = *(const uint4*)(tw + d * 32 + rb);
            uacc[nt] = __builtin_amdgcn_mfma_f32_16x16x32_bf16(af, *(bf16x8*)&bu, uacc[nt], 0, 0, 0);
        }
    }
    denacc += __shfl_xor(denacc, 16);
    denacc += __shfl_xor(denacc, 32);
    if (l < 8) dlds[w][l] = denacc;

    __syncthreads();
    float* vlds0 = (float*)&tiles[0][0];
    float* vlds1 = vlds0 + 1024;
    if (w < 2 && g < 2) {
        float* vb = (w == 0) ? vlds0 : vlds1;
#pragma unroll
        for (int nt = 0; nt < 8; nt++)
#pragma unroll
            for (int r = 0; r < 4; r++)
                vb[(g * 4 + r) * 128 + nt * 16 + c16] = uacc[nt][r];
    }
    __syncthreads();
    if (w >= 2 && g < 2) {
        float* vb = (w == 2) ? vlds0 : vlds1;
#pragma unroll
        for (int nt = 0; nt < 8; nt++)
#pragma unroll
            for (int r = 0; r < 4; r++)
                vb[(g * 4 + r) * 128 + nt * 16 + c16] += uacc[nt][r];
    }
    __syncthreads();
    float* vout = vecp + ((size_t)blk << 10);
#pragma unroll
    for (int rep = 0; rep < 4; rep++) {
        int o = rep * 256 + t;
        vout[o] = vlds0[o] + vlds1[o];
    }
    if (t < 8) denp[blk * 8 + t] = dlds[0][t] + dlds[1][t] + dlds[2][t] + dlds[3][t];
}

// ---------- K5: 512-thread parallel update ----------

__device__ inline float sum512(float v, float* red8) {
#pragma unroll
    for (int o = 32; o; o >>= 1) v += __shfl_down(v, o);
    __syncthreads();
    if ((threadIdx.x & 63) == 0) red8[threadIdx.x >> 6] = v;
    __syncthreads();
    float s = 0.f;
#pragma unroll
    for (int i = 0; i < 8; i++) s += red8[i];
    return s;
}

__device__ inline float reduce4(float part, float* praw, int qq, int d) {
    __syncthreads();
    praw[qq * 128 + d] = part;
    __syncthreads();
    return praw[d] + praw[128 + d] + praw[256 + d] + praw[384 + d];
}

__global__ __launch_bounds__(512) void k5_update(
    const float* __restrict__ vecp, const float* __restrict__ denp,
    const float* __restrict__ wv, const float* __restrict__ bv,
    const float* __restrict__ wihT, const float* __restrict__ whhT,
    const float* __restrict__ bih, const float* __restrict__ bhh,
    const float* __restrict__ lnfg, const float* __restrict__ lnfb,
    const float* __restrict__ m1w, const float* __restrict__ m1b,
    const float* __restrict__ m2w, const float* __restrict__ m2b,
    float* __restrict__ slots,
    const float* __restrict__ lnsg, const float* __restrict__ lnsb,
    const float* __restrict__ wq, const float* __restrict__ bq,
    const float* __restrict__ wkT, const float* __restrict__ bk,
    float* __restrict__ qt, float* __restrict__ qc,
    float* __restrict__ out, int compute_q, int write_out) {
    __shared__ float sA[128], sB[128], sC[128], sH[128], sQ[128];
    __shared__ float praw[512];
    __shared__ float red8[8];
    __shared__ float gsc[6][512];
    int t = threadIdx.x;
    int bs = blockIdx.x;
    int b = bs >> 3, slot = bs & 7;
    int d = t & 127, qq = t >> 7;

    float dvp = (t < 128) ? denp[((size_t)(b * 128) + t) * 8 + slot] : 0.f;
    float dv = sum512(dvp, red8);

    float vs = 0.f;
    const float* vp0 = vecp + (((size_t)(b * 128 + qq * 32)) << 10) + slot * 128 + d;
#pragma unroll 8
    for (int s = 0; s < 32; s++) vs += vp0[(size_t)s << 10];
    float vtot = reduce4(vs, praw, qq, d);
    if (qq == 0) { sA[d] = vtot / dv; sC[d] = slots[bs * 128 + d]; }
    __syncthreads();

    float up = 0.f;
    {
        const float* wvp = wv + (size_t)(qq * 32) * 128 + d;
#pragma unroll 8
        for (int i = 0; i < 32; i++) up = fmaf(sA[qq * 32 + i], wvp[i * 128], up);
    }
    float updt = reduce4(up, praw, qq, d) + bv[d];
    if (qq == 0) sB[d] = updt;
    __syncthreads();

#pragma unroll 1
    for (int gx = 0; gx < 3; gx++) {
        int g = gx * 128 + d;
        float ap = 0.f, hp = 0.f;
        const float* wi = wihT + (size_t)(qq * 32) * 384 + g;
        const float* wh = whhT + (size_t)(qq * 32) * 384 + g;
#pragma unroll 8
        for (int i = 0; i < 32; i++) {
            ap = fmaf(sB[qq * 32 + i], wi[i * 384], ap);
            hp = fmaf(sC[qq * 32 + i], wh[i * 384], hp);
        }
        gsc[gx * 2][t] = ap;
        gsc[gx * 2 + 1][t] = hp;
    }
    __syncthreads();
    float gi0 = gsc[0][d] + gsc[0][128 + d] + gsc[0][256 + d] + gsc[0][384 + d] + bih[d];
    float gh0 = gsc[1][d] + gsc[1][128 + d] + gsc[1][256 + d] + gsc[1][384 + d] + bhh[d];
    float gi1 = gsc[2][d] + gsc[2][128 + d] + gsc[2][256 + d] + gsc[2][384 + d] + bih[128 + d];
    float gh1 = gsc[3][d] + gsc[3][128 + d] + gsc[3][256 + d] + gsc[3][384 + d] + bhh[128 + d];
    float gi2 = gsc[4][d] + gsc[4][128 + d] + gsc[4][256 + d] + gsc[4][384 + d] + bih[256 + d];
    float gh2 = gsc[5][d] + gsc[5][128 + d] + gsc[5][256 + d] + gsc[5][384 + d] + bhh[256 + d];
    float rg = 1.f / (1.f + expf(-(gi0 + gh0)));
    float zg = 1.f / (1.f + expf(-(gi1 + gh1)));
    float ng = tanhf(fmaf(rg, gh2, gi2));
    float hnew = (1.f - zg) * ng + zg * sC[d];
    __syncthreads();
    if (qq == 0) sH[d] = hnew;
    __syncthreads();

    float xh = (t < 128) ? sH[t] : 0.f;
    float mh = sum512(xh, red8) * (1.0f / 128.0f);
    float eh = xh - mh;
    float vh = sum512((t < 128) ? eh * eh : 0.f, red8) * (1.0f / 128.0f);
    float invh = rsqrtf(vh + 1e-5f);
    __syncthreads();
    if (t < 128) sA[t] = fmaf(eh * invh, lnfg[t], lnfb[t]);
    __syncthreads();

    float p1 = 0.f;
    {
        const float* m1p = m1w + (size_t)(qq * 32) * 128 + d;
#pragma unroll 8
        for (int i = 0; i < 32; i++) p1 = fmaf(sA[qq * 32 + i], m1p[i * 128], p1);
    }
    float m1v = reduce4(p1, praw, qq, d) + m1b[d];
    if (qq == 0) sB[d] = m1v;
    __syncthreads();

    float p2 = 0.f;
    {
        const float* m2p = m2w + (size_t)(qq * 32) * 128 + d;
#pragma unroll 8
        for (int i = 0; i < 32; i++) p2 = fmaf(sB[qq * 32 + i], m2p[i * 128], p2);
    }
    float m2v = reduce4(p2, praw, qq, d) + m2b[d];
    float snew = sH[d] + m2v;
    __syncthreads();
    if (qq == 0) {
        slots[bs * 128 + d] = snew;
        if (write_out) out[bs * 128 + d] = snew;
        sH[d] = snew;
    }
    __syncthreads();

    if (compute_q) {
        float xs = (t < 128) ? sH[t] : 0.f;
        float ms = sum512(xs, red8) * (1.0f / 128.0f);
        float es = xs - ms;
        float vs2 = sum512((t < 128) ? es * es : 0.f, red8) * (1.0f / 128.0f);
        float invs = rsqrtf(vs2 + 1e-5f);
        __syncthreads();
        if (t < 128) sA[t] = fmaf(es * invs, lnsg[t], lnsb[t]);
        __syncthreads();
        float pq = 0.f;
        {
            const float* wqp = wq + (size_t)(qq * 32) * 128 + d;
#pragma unroll 8
            for (int i = 0; i < 32; i++) pq = fmaf(sA[qq * 32 + i], wqp[i * 128], pq);
        }
        float qv = reduce4(pq, praw, qq, d) + bq[d];
        if (qq == 0) sQ[d] = qv;
        __syncthreads();
        float pa = 0.f;
        {
            const float* wkp = wkT + (size_t)(qq * 32) * 128 + d;
#pragma unroll 8
            for (int j = 0; j < 32; j++) pa = fmaf(wkp[j * 128], sQ[qq * 32 + j], pa);
        }
        const float scale = 0.08838834764831845f;
        float a2 = reduce4(pa, praw, qq, d) * scale;
        if (qq == 0) qt[bs * 128 + d] = a2;
        float xpr = (t < 128) ? sQ[t] * bk[t] : 0.f;
        float pr = sum512(xpr, red8);
        if (t == 0) qc[bs] = pr * scale;
    }
}

// ---------- launch ----------

extern "C" void kernel_launch(void* const* d_in, const int* in_sizes, int n_in,
                              void* d_out, int out_size, void* d_ws, size_t ws_size,
                              hipStream_t stream) {
    const float* inputs = (const float*)d_in[0];
    const float* embed  = (const float*)d_in[1];
    const float* mu     = (const float*)d_in[2];
    const float* sg     = (const float*)d_in[3];
    const float* w0 = (const float*)d_in[4];  const float* b0 = (const float*)d_in[5];
    const float* w1 = (const float*)d_in[6];  const float* b1 = (const float*)d_in[7];
    const float* w2 = (const float*)d_in[8];  const float* b2 = (const float*)d_in[9];
    const float* w3 = (const float*)d_in[10]; const float* b3 = (const float*)d_in[11];
    const float* w4 = (const float*)d_in[12]; const float* b4 = (const float*)d_in[13];
    const float* w5 = (const float*)d_in[14]; const float* b5 = (const float*)d_in[15];
    const float* w7 = (const float*)d_in[16]; const float* b7 = (const float*)d_in[17];
    const float* wq = (const float*)d_in[18]; const float* bq = (const float*)d_in[19];
    const float* wk = (const float*)d_in[20]; const float* bk = (const float*)d_in[21];
    const float* wv = (const float*)d_in[22]; const float* bv = (const float*)d_in[23];
    const float* ln_in_g = (const float*)d_in[24]; const float* ln_in_b = (const float*)d_in[25];
    const float* ln_sl_g = (const float*)d_in[26]; const float* ln_sl_b = (const float*)d_in[27];
    const float* ln_ff_g = (const float*)d_in[28]; const float* ln_ff_b = (const float*)d_in[29];
    const float* gwih = (const float*)d_in[30]; const float* gwhh = (const float*)d_in[31];
    const float* gbih = (const float*)d_in[32]; const float* gbhh = (const float*)d_in[33];
    const float* m1w = (const float*)d_in[34]; const float* m1b = (const float*)d_in[35];
    const float* m2w = (const float*)d_in[36]; const float* m2b = (const float*)d_in[37];

    char* ws = (char*)d_ws;
    u16* hlnb = (u16*)ws;
    size_t off = (size_t)NB_ * 128 * 2;  // 64 MB bf16 hln row-major
    float* Wh    = (float*)(ws + off); off += 66 * 128 * 4;
    float* bh    = (float*)(ws + off); off += 128 * 4;
    float* slots = (float*)(ws + off); off += 64 * 128 * 4;
    float* qt    = (float*)(ws + off); off += 64 * 128 * 4;
    float* qc    = (float*)(ws + off); off += 64 * 4;
    float* vecp  = (float*)(ws + off); off += (size_t)1024 * 1024 * 4;  // 4 MB
    float* denp  = (float*)(ws + off); off += 1024 * 8 * 4;
    float* wihT  = (float*)(ws + off); off += 384 * 128 * 4;
    float* whhT  = (float*)(ws + off); off += 384 * 128 * 4;
    float* wkT   = (float*)(ws + off); off += 128 * 128 * 4;
    u16* whiT    = (u16*)(ws + off); off += 128 * 96 * 2;

    k0_transpose<<<448, 256, 0, stream>>>(gwih, gwhh, wk, wihT, whhT, wkT);
    k1_setup<<<1, 256, 0, stream>>>(w0, b0, w1, b1, w2, b2, w3, b3, w4, b4, w5, b5,
                                    w7, b7, mu, sg, Wh, bh, slots, whiT);
    k2_hln<<<NB_ / 128, 256, 0, stream>>>(inputs, embed, whiT, bh,
                                          ln_in_g, ln_in_b, hlnb);
    k3_q<<<64, 128, 0, stream>>>(slots, ln_sl_g, ln_sl_b, wq, bq, wkT, bk, qt, qc);
    for (int it = 0; it < 3; it++) {
        k4_attn<<<1024, 256, 0, stream>>>((const uint4*)hlnb, qt, qc, vecp, denp);
        k5_update<<<64, 512, 0, stream>>>(vecp, denp, wv, bv, wihT, whhT, gbih, gbhh,
                                          ln_ff_g, ln_ff_b, m1w, m1b, m2w, m2b, slots,
                                          ln_sl_g, ln_sl_b, wq, bq, wkT, bk, qt, qc,
                                          (float*)d_out, (it < 2) ? 1 : 0, (it == 2) ? 1 : 0);
    }
}

// Round 24
// 236.638 us; speedup vs baseline: 1.2318x; 1.0726x over previous
//
#include <hip/hip_runtime.h>

// SlotAttention (bf16 hln, single layout, MFMA). Round-23 structure +
// k2 staging split into issue-all-loads -> convert/write (T14 pattern):
// 34 outstanding loads/thread instead of 1 -> staging latency hidden.
//   - k2: single-bf16 MFMA GEMM; E pre-converted bf16 in LDS; lb(256,4).
//   - k4 x3: 1024 blocks x 4 waves x 2 pipelined 32-row tiles; stride-32
//     XOR-swizzled transposed tile; lb(256,4); per-slab partials.
//   - k5: 512 threads; GEMVs as 32-iter partials + LDS tree reduce.

#define B_  8
#define N_  32768
#define NB_ (B_ * N_)
#define D_  128
#define S_  8

typedef unsigned int u32;
typedef unsigned short u16;
typedef __attribute__((ext_vector_type(8))) short bf16x8;
typedef __attribute__((ext_vector_type(4))) float f32x4;

__device__ inline u32 bfr1(float x) {  // f32 -> bf16 (RNE)
    u32 u = __float_as_uint(x);
    return (u + 0x7FFFu + ((u >> 16) & 1u)) >> 16;
}
__device__ inline u32 bfpack2(u32 lo, u32 hi) { return lo | (hi << 16); }

// threefry2x32, key = (0, 42)
__device__ inline void threefry42(u32 c0, u32 c1, u32& o0, u32& o1) {
    const u32 k0 = 0u, k1 = 42u, k2 = 0x1BD11BDAu ^ 0u ^ 42u;
    const u32 ks[3] = {k0, k1, k2};
    u32 x0 = c0 + k0, x1 = c1 + k1;
    const int rA[4] = {13, 15, 26, 6}, rB[4] = {17, 29, 16, 24};
#pragma unroll
    for (int i = 0; i < 5; i++) {
#pragma unroll
        for (int k = 0; k < 4; k++) {
            int r = (i & 1) ? rB[k] : rA[k];
            x0 += x1;
            x1 = (x1 << r) | (x1 >> (32 - r));
            x1 ^= x0;
        }
        x0 += ks[(i + 1) % 3];
        x1 += ks[(i + 2) % 3] + (u32)(i + 1);
    }
    o0 = x0; o1 = x1;
}

// jax uniform(-0.99999994, 1) -> sqrt(2)*erfinv
__device__ inline float bits_to_normal(u32 b) {
    float f = __uint_as_float((b >> 9) | 0x3f800000u) - 1.0f;
    const float lo = -0.99999994f;
    float r = fmaxf(lo, f * 1.99999994f + lo);
    float w = -log1pf(-r * r);
    float p;
    if (w < 5.0f) {
        w -= 2.5f;
        p = 2.81022636e-08f;
        p = fmaf(p, w, 3.43273939e-07f);
        p = fmaf(p, w, -3.5233877e-06f);
        p = fmaf(p, w, -4.39150654e-06f);
        p = fmaf(p, w, 0.00021858087f);
        p = fmaf(p, w, -0.00125372503f);
        p = fmaf(p, w, -0.00417768164f);
        p = fmaf(p, w, 0.246640727f);
        p = fmaf(p, w, 1.50140941f);
    } else {
        w = sqrtf(w) - 3.0f;
        p = -0.000200214257f;
        p = fmaf(p, w, 0.000100950558f);
        p = fmaf(p, w, 0.00134934322f);
        p = fmaf(p, w, -0.00367342844f);
        p = fmaf(p, w, 0.00573950773f);
        p = fmaf(p, w, -0.0076224613f);
        p = fmaf(p, w, 0.00943887047f);
        p = fmaf(p, w, 1.00167406f);
        p = fmaf(p, w, 2.83297682f);
    }
    return 1.41421356f * (p * r);
}

// 128-thread block sum (k3 only)
__device__ inline float block128_sum(float v, float* red) {
#pragma unroll
    for (int o = 32; o; o >>= 1) v += __shfl_down(v, o);
    __syncthreads();
    if ((threadIdx.x & 63) == 0) red[threadIdx.x >> 6] = v;
    __syncthreads();
    return red[0] + red[1];
}

// emit_q for 128-thread k3
__device__ void emit_q(float x, int bs,
                       const float* lnsg, const float* lnsb,
                       const float* wq, const float* bq,
                       const float* wkT, const float* bk,
                       float* qt, float* qc,
                       float* shA, float* red) {
    int t = threadIdx.x;
    float m = block128_sum(x, red) * (1.0f / 128.0f);
    float e = x - m;
    float var = block128_sum(e * e, red) * (1.0f / 128.0f);
    float inv = rsqrtf(var + 1e-5f);
    __syncthreads();
    shA[t] = fmaf(e * inv, lnsg[t], lnsb[t]);
    __syncthreads();
    float q = bq[t];
#pragma unroll 4
    for (int i = 0; i < 128; i++) q = fmaf(shA[i], wq[i * 128 + t], q);
    __syncthreads();
    shA[t] = q;
    __syncthreads();
    float a2 = 0.f;
#pragma unroll 4
    for (int j = 0; j < 128; j++) a2 = fmaf(wkT[j * 128 + t], shA[j], a2);
    const float scale = 0.08838834764831845f;  // 128^-0.5
    qt[bs * 128 + t] = a2 * scale;
    float pr = block128_sum(shA[t] * bk[t], red);
    if (t == 0) qc[bs] = pr * scale;
}

// ---------- K0: transpose gru weights + wk ----------

__global__ __launch_bounds__(256) void k0_transpose(
    const float* __restrict__ wih, const float* __restrict__ whh,
    const float* __restrict__ wk,
    float* __restrict__ wihT, float* __restrict__ whhT, float* __restrict__ wkT) {
    int idx = blockIdx.x * 256 + threadIdx.x;
    if (idx < 49152) {
        int d = idx / 384, g = idx % 384;
        wihT[idx] = wih[g * 128 + d];
    } else if (idx < 98304) {
        int o = idx - 49152;
        int d = o / 384, g = o % 384;
        whhT[o] = whh[g * 128 + d];
    } else if (idx < 114688) {
        int o = idx - 98304;
        int j = o >> 7, tcol = o & 127;
        wkT[o] = wk[tcol * 128 + j];
    }
}

// ---------- K1: fold weights, init slots, bf16 W ----------

__global__ __launch_bounds__(256) void k1_setup(
    const float* __restrict__ w0, const float* __restrict__ b0,
    const float* __restrict__ w1, const float* __restrict__ b1,
    const float* __restrict__ w2, const float* __restrict__ b2,
    const float* __restrict__ w3, const float* __restrict__ b3,
    const float* __restrict__ w4, const float* __restrict__ b4,
    const float* __restrict__ w5, const float* __restrict__ b5,
    const float* __restrict__ w7, const float* __restrict__ b7,
    const float* __restrict__ mu, const float* __restrict__ sg,
    float* __restrict__ Wh, float* __restrict__ bh, float* __restrict__ slots,
    u16* __restrict__ whiT) {
    __shared__ float A[192], Bt[96], bb[64], bb2[32];
    __shared__ float stats[2];
    int t = threadIdx.x;
    for (int i = t; i < 192; i += 256) A[i] = w0[i];
    for (int i = t; i < 64; i += 256) bb[i] = b0[i];
    __syncthreads();
    const float* wl[5] = {w1, w2, w3, w4, w5};
    const float* bl[5] = {b1, b2, b3, b4, b5};
    int kin = 64;
    for (int l = 0; l < 5; l++) {
        const float* w = wl[l];
        const float* bias = bl[l];
        if (t < 96) {
            int i = t / 32, j = t % 32;
            float acc = 0.f;
            for (int k = 0; k < kin; k++) acc += A[i * kin + k] * w[k * 32 + j];
            Bt[i * 32 + j] = acc;
        } else if (t < 128) {
            int j = t - 96;
            float acc = bias[j];
            for (int k = 0; k < kin; k++) acc += bb[k] * w[k * 32 + j];
            bb2[j] = acc;
        }
        __syncthreads();
        if (t < 96) A[t] = Bt[t];
        if (t < 32) bb[t] = bb2[t];
        __syncthreads();
        kin = 32;
    }
    for (int idx = t; idx < 66 * 128; idx += 256) {
        int i = idx >> 7, j = idx & 127;
        float acc = w7[idx];
        if (i < 3) {
            for (int k = 0; k < 32; k++) acc += A[i * 32 + k] * w7[(66 + k) * 128 + j];
        }
        Wh[idx] = acc;
    }
    for (int j = t; j < 128; j += 256) {
        float acc = b7[j];
        for (int k = 0; k < 32; k++) acc += bb[k] * w7[(66 + k) * 128 + j];
        bh[j] = acc;
    }
    if (t == 0) {
        float s1 = 0.f, s2 = 0.f;
        for (int d = 0; d < 128; d++) { s1 += mu[d]; s2 += sg[d]; }
        float mmu = s1 / 128.f, msg = s2 / 128.f;
        float ss = 0.f;
        for (int d = 0; d < 128; d++) { float e = sg[d] - msg; ss += e * e; }
        stats[0] = mmu;
        stats[1] = sqrtf(64.f * ss / 8191.f);
    }
    __syncthreads();
    for (int idx = t; idx < 128 * 96; idx += 256) {
        int col = idx / 96, k = idx - col * 96;
        float v = (k < 66) ? Wh[k * 128 + col] : 0.f;
        whiT[idx] = (u16)bfr1(v);
    }
    float mean = stats[0], sd = stats[1];
    for (int p = t; p < 8192; p += 256) {
        u32 o0, o1;
        threefry42(0u, (u32)p, o0, o1);
        slots[p] = fmaf(sd, bits_to_normal(o0 ^ o1), mean);
    }
}

// ---------- K2: single-bf16 MFMA build of hln (async-split staging) ----------

__global__ __launch_bounds__(256, 4) void k2_hln(
    const float* __restrict__ inputs, const float* __restrict__ embed,
    const u16* __restrict__ whiT, const float* __restrict__ bh,
    const float* __restrict__ g, const float* __restrict__ bbias,
    u16* __restrict__ hlnb) {
    __shared__ __align__(16) char smem[34816];  // ebuf u16[128][104] / T u16[128][136]
    __shared__ float bhl[128], gl[128], bl[128];
    int t = threadIdx.x;
    u16* ebuf = (u16*)smem;
    size_t rbase = (size_t)blockIdx.x * 128;

    // ---- phase A: issue ALL global loads into registers (34/thread) ----
    float rin[2];
    float rem[32];
    const float* ibase = inputs + rbase * 3;
    const float* ebase = embed + rbase * 63;
#pragma unroll
    for (int k = 0; k < 2; k++) {
        int idx = t + k * 256;
        rin[k] = (idx < 384) ? ibase[idx] : 0.f;
    }
#pragma unroll
    for (int k = 0; k < 31; k++) rem[k] = ebase[t + k * 256];
    rem[31] = (t < 128) ? ebase[t + 7936] : 0.f;
    if (t < 128) { bhl[t] = bh[t]; gl[t] = g[t]; bl[t] = bbias[t]; }

    // ---- phase B: convert + scatter to LDS ----
#pragma unroll
    for (int k = 0; k < 2; k++) {
        int idx = t + k * 256;
        if (idx < 384) ebuf[(idx / 3) * 104 + (idx % 3)] = (u16)bfr1(rin[k]);
    }
#pragma unroll
    for (int k = 0; k < 31; k++) {
        int idx = t + k * 256;
        int r = idx / 63, i = idx - r * 63;
        ebuf[r * 104 + 3 + i] = (u16)bfr1(rem[k]);
    }
    if (t < 128) {
        int idx = t + 7936;
        int r = idx / 63, i = idx - r * 63;
        ebuf[r * 104 + 3 + i] = (u16)bfr1(rem[31]);
    }
    for (int idx = t; idx < 128 * 30; idx += 256) {
        int r = idx / 30, i = idx - r * 30;
        ebuf[r * 104 + 66 + i] = 0;
    }
    __syncthreads();

    int w = t >> 6, l = t & 63;
    int c16 = l & 15, g4 = l >> 4;
    int wr0 = w * 32;
    float bhc[8], gc[8], bc[8];
#pragma unroll
    for (int nt = 0; nt < 8; nt++) {
        bhc[nt] = bhl[nt * 16 + c16];
        gc[nt] = gl[nt * 16 + c16];
        bc[nt] = bl[nt * 16 + c16];
    }
    f32x4 acc[2][8];
#pragma unroll
    for (int mi = 0; mi < 2; mi++)
#pragma unroll
        for (int nt = 0; nt < 8; nt++)
            acc[mi][nt] = (f32x4){bhc[nt], bhc[nt], bhc[nt], bhc[nt]};

#pragma unroll
    for (int kc = 0; kc < 3; kc++) {
        bf16x8 a0 = *(const bf16x8*)&ebuf[(wr0 + c16) * 104 + kc * 32 + g4 * 8];
        bf16x8 a1 = *(const bf16x8*)&ebuf[(wr0 + 16 + c16) * 104 + kc * 32 + g4 * 8];
#pragma unroll
        for (int nt = 0; nt < 8; nt++) {
            uint4 bw = *(const uint4*)(whiT + (size_t)(nt * 16 + c16) * 96 + kc * 32 + g4 * 8);
            bf16x8 bf = *(bf16x8*)&bw;
            acc[0][nt] = __builtin_amdgcn_mfma_f32_16x16x32_bf16(a0, bf, acc[0][nt], 0, 0, 0);
            acc[1][nt] = __builtin_amdgcn_mfma_f32_16x16x32_bf16(a1, bf, acc[1][nt], 0, 0, 0);
        }
    }

    __syncthreads();
    u16* T = (u16*)smem;           // [128][136]
#pragma unroll
    for (int mi = 0; mi < 2; mi++) {
#pragma unroll
        for (int i = 0; i < 4; i++) {
            float s = 0.f;
#pragma unroll
            for (int nt = 0; nt < 8; nt++) s += acc[mi][nt][i];
            s += __shfl_xor(s, 1); s += __shfl_xor(s, 2);
            s += __shfl_xor(s, 4); s += __shfl_xor(s, 8);
            float m = s * (1.0f / 128.0f);
            float v = 0.f;
#pragma unroll
            for (int nt = 0; nt < 8; nt++) { float d = acc[mi][nt][i] - m; v = fmaf(d, d, v); }
            v += __shfl_xor(v, 1); v += __shfl_xor(v, 2);
            v += __shfl_xor(v, 4); v += __shfl_xor(v, 8);
            float inv = rsqrtf(v * (1.0f / 128.0f) + 1e-5f);
            int row = wr0 + mi * 16 + g4 * 4 + i;
#pragma unroll
            for (int nt = 0; nt < 8; nt++) {
                float val = fmaf((acc[mi][nt][i] - m) * inv, gc[nt], bc[nt]);
                T[row * 136 + nt * 16 + c16] = (u16)bfr1(val);
            }
        }
    }
    __syncthreads();
    {
        int r = t >> 1, hf = t & 1;
        const u16* Tr = T + r * 136 + hf * 64;
        u16* dst = hlnb + (rbase + r) * 128 + hf * 64;
#pragma unroll
        for (int j = 0; j < 8; j++) {
            uint4 v = *(const uint4*)(Tr + j * 8);
            *(uint4*)(dst + j * 8) = v;
        }
    }
}

// ---------- K3: initial q from slots ----------

__global__ __launch_bounds__(128) void k3_q(
    const float* __restrict__ slots,
    const float* __restrict__ lnsg, const float* __restrict__ lnsb,
    const float* __restrict__ wq, const float* __restrict__ bq,
    const float* __restrict__ wkT, const float* __restrict__ bk,
    float* __restrict__ qt, float* __restrict__ qc) {
    __shared__ float shA[128];
    __shared__ float red[2];
    int bs = blockIdx.x;
    float x = slots[bs * 128 + threadIdx.x];
    emit_q(x, bs, lnsg, lnsb, wq, bq, wkT, bk, qt, qc, shA, red);
}

// ---------- K4: MFMA attention, 2 pipelined tiles/wave ----------

__global__ __launch_bounds__(256, 4) void k4_attn(
    const uint4* __restrict__ hlnb4,
    const float* __restrict__ qt, const float* __restrict__ qc,
    float* __restrict__ vecp, float* __restrict__ denp) {
    __shared__ __align__(16) u16 tiles[4][128 * 32];   // 32768 B (vlds aliased)
    __shared__ __align__(16) u16 attnP[4][16 * 40];    // 5120 B
    __shared__ float dlds[4][8];
    int t = threadIdx.x;
    int w = t >> 6, l = t & 63;
    int blk = blockIdx.x;
    int b = blk >> 7, slab = blk & 127;
    size_t row0 = (size_t)b * N_ + (size_t)slab * 256 + (size_t)w * 32;
    int c16 = l & 15, g = l >> 4;
    u16* tw = tiles[w];

    bf16x8 qf[4];
#pragma unroll
    for (int kc = 0; kc < 4; kc++) {
        uint4 qu = {0u, 0u, 0u, 0u};
        if (c16 < 8) {
            const float* qp = qt + b * 1024 + c16 * 128 + kc * 32 + g * 8;
            float4 qa = *(const float4*)qp;
            float4 qb = *(const float4*)(qp + 4);
            qu.x = bfpack2(bfr1(qa.x), bfr1(qa.y));
            qu.y = bfpack2(bfr1(qa.z), bfr1(qa.w));
            qu.z = bfpack2(bfr1(qb.x), bfr1(qb.y));
            qu.w = bfpack2(bfr1(qb.z), bfr1(qb.w));
        }
        qf[kc] = *(bf16x8*)&qu;
    }
    float qcv = (c16 < 8) ? qc[b * 8 + c16] : 0.f;

    f32x4 uacc[8];
#pragma unroll
    for (int nt = 0; nt < 8; nt++) uacc[nt] = (f32x4){0.f, 0.f, 0.f, 0.f};
    float denacc = 0.f;

    uint4 st[8];
#pragma unroll
    for (int mt = 0; mt < 2; mt++)
#pragma unroll
        for (int kc = 0; kc < 4; kc++)
            st[mt * 4 + kc] = hlnb4[(row0 + mt * 16 + c16) * 16 + kc * 4 + g];

    for (int tt = 0; tt < 2; tt++) {
        f32x4 dacc[2];
        dacc[0] = (f32x4){0.f, 0.f, 0.f, 0.f};
        dacc[1] = (f32x4){0.f, 0.f, 0.f, 0.f};
#pragma unroll
        for (int mt = 0; mt < 2; mt++) {
#pragma unroll
            for (int kc = 0; kc < 4; kc++) {
                uint4 au = st[mt * 4 + kc];
                dacc[mt] = __builtin_amdgcn_mfma_f32_16x16x32_bf16(*(bf16x8*)&au, qf[kc], dacc[mt], 0, 0, 0);
                int r = mt * 16 + c16;
                int d0 = kc * 32 + g * 8;
                int d;
                d = d0 + 0; tw[d * 32 + (r ^ (((d >> 1) & 3) << 3))] = (u16)(au.x & 0xFFFF);
                d = d0 + 1; tw[d * 32 + (r ^ (((d >> 1) & 3) << 3))] = (u16)(au.x >> 16);
                d = d0 + 2; tw[d * 32 + (r ^ (((d >> 1) & 3) << 3))] = (u16)(au.y & 0xFFFF);
                d = d0 + 3; tw[d * 32 + (r ^ (((d >> 1) & 3) << 3))] = (u16)(au.y >> 16);
                d = d0 + 4; tw[d * 32 + (r ^ (((d >> 1) & 3) << 3))] = (u16)(au.z & 0xFFFF);
                d = d0 + 5; tw[d * 32 + (r ^ (((d >> 1) & 3) << 3))] = (u16)(au.z >> 16);
                d = d0 + 6; tw[d * 32 + (r ^ (((d >> 1) & 3) << 3))] = (u16)(au.w & 0xFFFF);
                d = d0 + 7; tw[d * 32 + (r ^ (((d >> 1) & 3) << 3))] = (u16)(au.w >> 16);
            }
        }
        if (tt == 0) {
            size_t rowB = row0 + 128;
#pragma unroll
            for (int mt = 0; mt < 2; mt++)
#pragma unroll
                for (int kc = 0; kc < 4; kc++)
                    st[mt * 4 + kc] = hlnb4[(rowB + mt * 16 + c16) * 16 + kc * 4 + g];
        }
#pragma unroll
        for (int mt = 0; mt < 2; mt++) {
            float pv[4];
#pragma unroll
            for (int r = 0; r < 4; r++) {
                float v = dacc[mt][r] + qcv;
                float mx = v;
                mx = fmaxf(mx, __shfl_xor(mx, 1));
                mx = fmaxf(mx, __shfl_xor(mx, 2));
                mx = fmaxf(mx, __shfl_xor(mx, 4));
                float e = __expf(v - mx);
                float ssum = e;
                ssum += __shfl_xor(ssum, 1);
                ssum += __shfl_xor(ssum, 2);
                ssum += __shfl_xor(ssum, 4);
                float a = (c16 < 8) ? fmaf(e, 1.0f / ssum, 1e-8f) : 0.f;
                pv[r] = a;
                denacc += a;
            }
            uint2 pw;
            pw.x = bfpack2(bfr1(pv[0]), bfr1(pv[1]));
            pw.y = bfpack2(bfr1(pv[2]), bfr1(pv[3]));
            *(uint2*)&attnP[w][c16 * 40 + mt * 16 + g * 4] = pw;
        }
        uint4 afu = *(const uint4*)&attnP[w][c16 * 40 + g * 8];
        bf16x8 af = *(bf16x8*)&afu;
#pragma unroll
        for (int nt = 0; nt < 8; nt++) {
            int d = nt * 16 + c16;
            int rb = (g * 8) ^ (((d >> 1) & 3) << 3);
            uint4 bu = *(const uint4*)(tw + d * 32 + rb);
            uacc[nt] = __builtin_amdgcn_mfma_f32_16x16x32_bf16(af, *(bf16x8*)&bu, uacc[nt], 0, 0, 0);
        }
    }
    denacc += __shfl_xor(denacc, 16);
    denacc += __shfl_xor(denacc, 32);
    if (l < 8) dlds[w][l] = denacc;

    __syncthreads();
    float* vlds0 = (float*)&tiles[0][0];
    float* vlds1 = vlds0 + 1024;
    if (w < 2 && g < 2) {
        float* vb = (w == 0) ? vlds0 : vlds1;
#pragma unroll
        for (int nt = 0; nt < 8; nt++)
#pragma unroll
            for (int r = 0; r < 4; r++)
                vb[(g * 4 + r) * 128 + nt * 16 + c16] = uacc[nt][r];
    }
    __syncthreads();
    if (w >= 2 && g < 2) {
        float* vb = (w == 2) ? vlds0 : vlds1;
#pragma unroll
        for (int nt = 0; nt < 8; nt++)
#pragma unroll
            for (int r = 0; r < 4; r++)
                vb[(g * 4 + r) * 128 + nt * 16 + c16] += uacc[nt][r];
    }
    __syncthreads();
    float* vout = vecp + ((size_t)blk << 10);
#pragma unroll
    for (int rep = 0; rep < 4; rep++) {
        int o = rep * 256 + t;
        vout[o] = vlds0[o] + vlds1[o];
    }
    if (t < 8) denp[blk * 8 + t] = dlds[0][t] + dlds[1][t] + dlds[2][t] + dlds[3][t];
}

// ---------- K5: 512-thread parallel update ----------

__device__ inline float sum512(float v, float* red8) {
#pragma unroll
    for (int o = 32; o; o >>= 1) v += __shfl_down(v, o);
    __syncthreads();
    if ((threadIdx.x & 63) == 0) red8[threadIdx.x >> 6] = v;
    __syncthreads();
    float s = 0.f;
#pragma unroll
    for (int i = 0; i < 8; i++) s += red8[i];
    return s;
}

__device__ inline float reduce4(float part, float* praw, int qq, int d) {
    __syncthreads();
    praw[qq * 128 + d] = part;
    __syncthreads();
    return praw[d] + praw[128 + d] + praw[256 + d] + praw[384 + d];
}

__global__ __launch_bounds__(512) void k5_update(
    const float* __restrict__ vecp, const float* __restrict__ denp,
    const float* __restrict__ wv, const float* __restrict__ bv,
    const float* __restrict__ wihT, const float* __restrict__ whhT,
    const float* __restrict__ bih, const float* __restrict__ bhh,
    const float* __restrict__ lnfg, const float* __restrict__ lnfb,
    const float* __restrict__ m1w, const float* __restrict__ m1b,
    const float* __restrict__ m2w, const float* __restrict__ m2b,
    float* __restrict__ slots,
    const float* __restrict__ lnsg, const float* __restrict__ lnsb,
    const float* __restrict__ wq, const float* __restrict__ bq,
    const float* __restrict__ wkT, const float* __restrict__ bk,
    float* __restrict__ qt, float* __restrict__ qc,
    float* __restrict__ out, int compute_q, int write_out) {
    __shared__ float sA[128], sB[128], sC[128], sH[128], sQ[128];
    __shared__ float praw[512];
    __shared__ float red8[8];
    __shared__ float gsc[6][512];
    int t = threadIdx.x;
    int bs = blockIdx.x;
    int b = bs >> 3, slot = bs & 7;
    int d = t & 127, qq = t >> 7;

    float dvp = (t < 128) ? denp[((size_t)(b * 128) + t) * 8 + slot] : 0.f;
    float dv = sum512(dvp, red8);

    float vs = 0.f;
    const float* vp0 = vecp + (((size_t)(b * 128 + qq * 32)) << 10) + slot * 128 + d;
#pragma unroll 8
    for (int s = 0; s < 32; s++) vs += vp0[(size_t)s << 10];
    float vtot = reduce4(vs, praw, qq, d);
    if (qq == 0) { sA[d] = vtot / dv; sC[d] = slots[bs * 128 + d]; }
    __syncthreads();

    float up = 0.f;
    {
        const float* wvp = wv + (size_t)(qq * 32) * 128 + d;
#pragma unroll 8
        for (int i = 0; i < 32; i++) up = fmaf(sA[qq * 32 + i], wvp[i * 128], up);
    }
    float updt = reduce4(up, praw, qq, d) + bv[d];
    if (qq == 0) sB[d] = updt;
    __syncthreads();

#pragma unroll 1
    for (int gx = 0; gx < 3; gx++) {
        int g = gx * 128 + d;
        float ap = 0.f, hp = 0.f;
        const float* wi = wihT + (size_t)(qq * 32) * 384 + g;
        const float* wh = whhT + (size_t)(qq * 32) * 384 + g;
#pragma unroll 8
        for (int i = 0; i < 32; i++) {
            ap = fmaf(sB[qq * 32 + i], wi[i * 384], ap);
            hp = fmaf(sC[qq * 32 + i], wh[i * 384], hp);
        }
        gsc[gx * 2][t] = ap;
        gsc[gx * 2 + 1][t] = hp;
    }
    __syncthreads();
    float gi0 = gsc[0][d] + gsc[0][128 + d] + gsc[0][256 + d] + gsc[0][384 + d] + bih[d];
    float gh0 = gsc[1][d] + gsc[1][128 + d] + gsc[1][256 + d] + gsc[1][384 + d] + bhh[d];
    float gi1 = gsc[2][d] + gsc[2][128 + d] + gsc[2][256 + d] + gsc[2][384 + d] + bih[128 + d];
    float gh1 = gsc[3][d] + gsc[3][128 + d] + gsc[3][256 + d] + gsc[3][384 + d] + bhh[128 + d];
    float gi2 = gsc[4][d] + gsc[4][128 + d] + gsc[4][256 + d] + gsc[4][384 + d] + bih[256 + d];
    float gh2 = gsc[5][d] + gsc[5][128 + d] + gsc[5][256 + d] + gsc[5][384 + d] + bhh[256 + d];
    float rg = 1.f / (1.f + expf(-(gi0 + gh0)));
    float zg = 1.f / (1.f + expf(-(gi1 + gh1)));
    float ng = tanhf(fmaf(rg, gh2, gi2));
    float hnew = (1.f - zg) * ng + zg * sC[d];
    __syncthreads();
    if (qq == 0) sH[d] = hnew;
    __syncthreads();

    float xh = (t < 128) ? sH[t] : 0.f;
    float mh = sum512(xh, red8) * (1.0f / 128.0f);
    float eh = xh - mh;
    float vh = sum512((t < 128) ? eh * eh : 0.f, red8) * (1.0f / 128.0f);
    float invh = rsqrtf(vh + 1e-5f);
    __syncthreads();
    if (t < 128) sA[t] = fmaf(eh * invh, lnfg[t], lnfb[t]);
    __syncthreads();

    float p1 = 0.f;
    {
        const float* m1p = m1w + (size_t)(qq * 32) * 128 + d;
#pragma unroll 8
        for (int i = 0; i < 32; i++) p1 = fmaf(sA[qq * 32 + i], m1p[i * 128], p1);
    }
    float m1v = reduce4(p1, praw, qq, d) + m1b[d];
    if (qq == 0) sB[d] = m1v;
    __syncthreads();

    float p2 = 0.f;
    {
        const float* m2p = m2w + (size_t)(qq * 32) * 128 + d;
#pragma unroll 8
        for (int i = 0; i < 32; i++) p2 = fmaf(sB[qq * 32 + i], m2p[i * 128], p2);
    }
    float m2v = reduce4(p2, praw, qq, d) + m2b[d];
    float snew = sH[d] + m2v;
    __syncthreads();
    if (qq == 0) {
        slots[bs * 128 + d] = snew;
        if (write_out) out[bs * 128 + d] = snew;
        sH[d] = snew;
    }
    __syncthreads();

    if (compute_q) {
        float xs = (t < 128) ? sH[t] : 0.f;
        float ms = sum512(xs, red8) * (1.0f / 128.0f);
        float es = xs - ms;
        float vs2 = sum512((t < 128) ? es * es : 0.f, red8) * (1.0f / 128.0f);
        float invs = rsqrtf(vs2 + 1e-5f);
        __syncthreads();
        if (t < 128) sA[t] = fmaf(es * invs, lnsg[t], lnsb[t]);
        __syncthreads();
        float pq = 0.f;
        {
            const float* wqp = wq + (size_t)(qq * 32) * 128 + d;
#pragma unroll 8
            for (int i = 0; i < 32; i++) pq = fmaf(sA[qq * 32 + i], wqp[i * 128], pq);
        }
        float qv = reduce4(pq, praw, qq, d) + bq[d];
        if (qq == 0) sQ[d] = qv;
        __syncthreads();
        float pa = 0.f;
        {
            const float* wkp = wkT + (size_t)(qq * 32) * 128 + d;
#pragma unroll 8
            for (int j = 0; j < 32; j++) pa = fmaf(wkp[j * 128], sQ[qq * 32 + j], pa);
        }
        const float scale = 0.08838834764831845f;
        float a2 = reduce4(pa, praw, qq, d) * scale;
        if (qq == 0) qt[bs * 128 + d] = a2;
        float xpr = (t < 128) ? sQ[t] * bk[t] : 0.f;
        float pr = sum512(xpr, red8);
        if (t == 0) qc[bs] = pr * scale;
    }
}

// ---------- launch ----------

extern "C" void kernel_launch(void* const* d_in, const int* in_sizes, int n_in,
                              void* d_out, int out_size, void* d_ws, size_t ws_size,
                              hipStream_t stream) {
    const float* inputs = (const float*)d_in[0];
    const float* embed  = (const float*)d_in[1];
    const float* mu     = (const float*)d_in[2];
    const float* sg     = (const float*)d_in[3];
    const float* w0 = (const float*)d_in[4];  const float* b0 = (const float*)d_in[5];
    const float* w1 = (const float*)d_in[6];  const float* b1 = (const float*)d_in[7];
    const float* w2 = (const float*)d_in[8];  const float* b2 = (const float*)d_in[9];
    const float* w3 = (const float*)d_in[10]; const float* b3 = (const float*)d_in[11];
    const float* w4 = (const float*)d_in[12]; const float* b4 = (const float*)d_in[13];
    const float* w5 = (const float*)d_in[14]; const float* b5 = (const float*)d_in[15];
    const float* w7 = (const float*)d_in[16]; const float* b7 = (const float*)d_in[17];
    const float* wq = (const float*)d_in[18]; const float* bq = (const float*)d_in[19];
    const float* wk = (const float*)d_in[20]; const float* bk = (const float*)d_in[21];
    const float* wv = (const float*)d_in[22]; const float* bv = (const float*)d_in[23];
    const float* ln_in_g = (const float*)d_in[24]; const float* ln_in_b = (const float*)d_in[25];
    const float* ln_sl_g = (const float*)d_in[26]; const float* ln_sl_b = (const float*)d_in[27];
    const float* ln_ff_g = (const float*)d_in[28]; const float* ln_ff_b = (const float*)d_in[29];
    const float* gwih = (const float*)d_in[30]; const float* gwhh = (const float*)d_in[31];
    const float* gbih = (const float*)d_in[32]; const float* gbhh = (const float*)d_in[33];
    const float* m1w = (const float*)d_in[34]; const float* m1b = (const float*)d_in[35];
    const float* m2w = (const float*)d_in[36]; const float* m2b = (const float*)d_in[37];

    char* ws = (char*)d_ws;
    u16* hlnb = (u16*)ws;
    size_t off = (size_t)NB_ * 128 * 2;  // 64 MB bf16 hln row-major
    float* Wh    = (float*)(ws + off); off += 66 * 128 * 4;
    float* bh    = (float*)(ws + off); off += 128 * 4;
    float* slots = (float*)(ws + off); off += 64 * 128 * 4;
    float* qt    = (float*)(ws + off); off += 64 * 128 * 4;
    float* qc    = (float*)(ws + off); off += 64 * 4;
    float* vecp  = (float*)(ws + off); off += (size_t)1024 * 1024 * 4;  // 4 MB
    float* denp  = (float*)(ws + off); off += 1024 * 8 * 4;
    float* wihT  = (float*)(ws + off); off += 384 * 128 * 4;
    float* whhT  = (float*)(ws + off); off += 384 * 128 * 4;
    float* wkT   = (float*)(ws + off); off += 128 * 128 * 4;
    u16* whiT    = (u16*)(ws + off); off += 128 * 96 * 2;

    k0_transpose<<<448, 256, 0, stream>>>(gwih, gwhh, wk, wihT, whhT, wkT);
    k1_setup<<<1, 256, 0, stream>>>(w0, b0, w1, b1, w2, b2, w3, b3, w4, b4, w5, b5,
                                    w7, b7, mu, sg, Wh, bh, slots, whiT);
    k2_hln<<<NB_ / 128, 256, 0, stream>>>(inputs, embed, whiT, bh,
                                          ln_in_g, ln_in_b, hlnb);
    k3_q<<<64, 128, 0, stream>>>(slots, ln_sl_g, ln_sl_b, wq, bq, wkT, bk, qt, qc);
    for (int it = 0; it < 3; it++) {
        k4_attn<<<1024, 256, 0, stream>>>((const uint4*)hlnb, qt, qc, vecp, denp);
        k5_update<<<64, 512, 0, stream>>>(vecp, denp, wv, bv, wihT, whhT, gbih, gbhh,
                                          ln_ff_g, ln_ff_b, m1w, m1b, m2w, m2b, slots,
                                          ln_sl_g, ln_sl_b, wq, bq, wkT, bk, qt, qc,
                                          (float*)d_out, (it < 2) ? 1 : 0, (it == 2) ? 1 : 0);
    }
}